// Round 1
// baseline (621.503 us; speedup 1.0000x reference)
//
#include <hip/hip_runtime.h>
#include <math.h>

#define H 128
#define R 32
#define NATOMS 2048
#define NEDGES 32768
#define NH (NATOMS * H)          // 262144 (n,h) pairs
#define CUTOFF_F 4.5f
#define PI_OVER_CUTOFF 0.6981317007977318f

#define BM 64
#define BN 64
#define BK 32

// ---------------------------------------------------------------------------
// silu
__device__ __forceinline__ float silu_f(float x) {
    return x / (1.f + __expf(-x));
}

// Build full 3x3 from decomposition [i0, a01, a02, a12, s00, s01, s02, s11, s12]
__device__ __forceinline__ void build_full(const float d[9], float m[9]) {
    float i0 = d[0], a01 = d[1], a02 = d[2], a12 = d[3];
    float s00 = d[4], s01 = d[5], s02 = d[6], s11 = d[7], s12 = d[8];
    float s22 = -(s00 + s11);
    m[0] = i0 + s00;  m[1] = a01 + s01;  m[2] = a02 + s02;
    m[3] = s01 - a01; m[4] = i0 + s11;   m[5] = a12 + s12;
    m[6] = s02 - a02; m[7] = s12 - a12;  m[8] = i0 + s22;
}

// ---------------------------------------------------------------------------
// Node prep: X -> Xn (normalized, [nh][9]) and decomposition D (9 planes of NH)
__global__ __launch_bounds__(256) void k_node_prep(
        const float* __restrict__ X, float* __restrict__ Xn,
        float* __restrict__ D) {
    int i = blockIdx.x * 256 + threadIdx.x;
    if (i >= NH) return;
    const float* x = X + (size_t)i * 9;
    float v[9];
    float ss = 0.f;
#pragma unroll
    for (int j = 0; j < 9; j++) { v[j] = x[j]; ss += v[j] * v[j]; }
    float inv = 1.f / (ss + 1.f);
#pragma unroll
    for (int j = 0; j < 9; j++) { v[j] *= inv; Xn[(size_t)i * 9 + j] = v[j]; }
    float i0 = (v[0] + v[4] + v[8]) * (1.f / 3.f);
    D[0 * NH + i] = i0;
    D[1 * NH + i] = 0.5f * (v[1] - v[3]);
    D[2 * NH + i] = 0.5f * (v[2] - v[6]);
    D[3 * NH + i] = 0.5f * (v[5] - v[7]);
    D[4 * NH + i] = v[0] - i0;
    D[5 * NH + i] = 0.5f * (v[1] + v[3]);
    D[6 * NH + i] = 0.5f * (v[2] + v[6]);
    D[7 * NH + i] = v[4] - i0;
    D[8 * NH + i] = 0.5f * (v[5] + v[7]);
}

// ---------------------------------------------------------------------------
// Generic fp32 tile GEMM body: Out[m,n] = epilogue( sum_k A[m,k]*W[n,k] )
// MODE 0: plain; MODE 1: +bias, silu; MODE 2: +bias, silu, *cosine-cutoff(ew[m])
template <int MODE>
__device__ __forceinline__ void gemm_tile_body(
        const float* __restrict__ A, const float* __restrict__ W,
        const float* __restrict__ bias, const float* __restrict__ ew,
        float* __restrict__ Out, int K, int N, int m0, int n0) {
    __shared__ float As[BK][BM + 4];
    __shared__ float Bs[BK][BN + 4];
    int t = threadIdx.x;
    int tn = t & 15, tm = t >> 4;
    int r0 = tm * 4, c0 = tn * 4;
    float acc[4][4];
#pragma unroll
    for (int i = 0; i < 4; i++)
#pragma unroll
        for (int j = 0; j < 4; j++) acc[i][j] = 0.f;

    for (int k0 = 0; k0 < K; k0 += BK) {
#pragma unroll
        for (int i = 0; i < 2; i++) {
            int idx = t * 2 + i;          // 0..511 float4 slots
            int m = idx >> 3, k4 = idx & 7;
            float4 va = *(const float4*)&A[(size_t)(m0 + m) * K + k0 + k4 * 4];
            As[k4 * 4 + 0][m] = va.x; As[k4 * 4 + 1][m] = va.y;
            As[k4 * 4 + 2][m] = va.z; As[k4 * 4 + 3][m] = va.w;
            float4 vb = *(const float4*)&W[(size_t)(n0 + m) * K + k0 + k4 * 4];
            Bs[k4 * 4 + 0][m] = vb.x; Bs[k4 * 4 + 1][m] = vb.y;
            Bs[k4 * 4 + 2][m] = vb.z; Bs[k4 * 4 + 3][m] = vb.w;
        }
        __syncthreads();
#pragma unroll
        for (int kk = 0; kk < BK; kk++) {
            float4 a4 = *(const float4*)&As[kk][r0];
            float4 b4 = *(const float4*)&Bs[kk][c0];
            float av[4] = {a4.x, a4.y, a4.z, a4.w};
            float bv[4] = {b4.x, b4.y, b4.z, b4.w};
#pragma unroll
            for (int i = 0; i < 4; i++)
#pragma unroll
                for (int j = 0; j < 4; j++)
                    acc[i][j] = fmaf(av[i], bv[j], acc[i][j]);
        }
        __syncthreads();
    }

    float bb[4] = {0.f, 0.f, 0.f, 0.f};
    if (MODE >= 1) {
        bb[0] = bias[n0 + c0];     bb[1] = bias[n0 + c0 + 1];
        bb[2] = bias[n0 + c0 + 2]; bb[3] = bias[n0 + c0 + 3];
    }
    float cs[4] = {1.f, 1.f, 1.f, 1.f};
    if (MODE == 2) {
#pragma unroll
        for (int i = 0; i < 4; i++) {
            float w = ew[m0 + r0 + i];
            cs[i] = (w < CUTOFF_F) ? 0.5f * (__cosf(w * PI_OVER_CUTOFF) + 1.f) : 0.f;
        }
    }
#pragma unroll
    for (int i = 0; i < 4; i++) {
        float4 o;
        float* op = &o.x;
#pragma unroll
        for (int j = 0; j < 4; j++) {
            float x = acc[i][j];
            if (MODE >= 1) { x += bb[j]; x = silu_f(x); }
            if (MODE == 2) { x *= cs[i]; }
            op[j] = x;
        }
        *(float4*)&Out[(size_t)(m0 + r0 + i) * N + n0 + c0] = o;
    }
}

template <int MODE>
__global__ __launch_bounds__(256) void k_gemm(
        const float* __restrict__ A, const float* __restrict__ W,
        const float* __restrict__ bias, const float* __restrict__ ew,
        float* __restrict__ Out, int K, int N) {
    gemm_tile_body<MODE>(A, W, bias, ew, Out, K, N,
                         blockIdx.x * BM, blockIdx.y * BN);
}

// Channel-mix batched GEMM: 9 component planes; plane c uses Wt part (0|1|2)
__global__ __launch_bounds__(256) void k_gemm_mix(
        const float* __restrict__ Din, const float* __restrict__ Wtbase,
        float* __restrict__ Outp) {
    int c = blockIdx.z;
    int part = (c == 0) ? 0 : ((c < 4) ? 1 : 2);
    gemm_tile_body<0>(Din + (size_t)c * NH, Wtbase + part * H * H,
                      nullptr, nullptr, Outp + (size_t)c * NH,
                      H, H, blockIdx.x * BM, blockIdx.y * BN);
}

// ---------------------------------------------------------------------------
// Edge message scatter: Mdec[src] += ea .* Ydec[dst]  (decomposed, 9 comps)
__global__ __launch_bounds__(256) void k_scatter(
        const float* __restrict__ ea, const int* __restrict__ eidx,
        const float* __restrict__ Ydec, float* __restrict__ Mdec,
        int e0, int nE) {
    int gid = blockIdx.x * 256 + threadIdx.x;
    if (gid >= nE * H) return;
    int el = gid >> 7;
    int h = gid & 127;
    int e = e0 + el;
    int src = eidx[e];
    int dst = eidx[NEDGES + e];
    float ea0 = ea[(size_t)el * 384 + h * 3 + 0];
    float ea1 = ea[(size_t)el * 384 + h * 3 + 1];
    float ea2 = ea[(size_t)el * 384 + h * 3 + 2];
    int db = dst * H + h, sb = src * H + h;
    atomicAdd(&Mdec[0 * NH + sb], ea0 * Ydec[0 * NH + db]);
    atomicAdd(&Mdec[1 * NH + sb], ea1 * Ydec[1 * NH + db]);
    atomicAdd(&Mdec[2 * NH + sb], ea1 * Ydec[2 * NH + db]);
    atomicAdd(&Mdec[3 * NH + sb], ea1 * Ydec[3 * NH + db]);
    atomicAdd(&Mdec[4 * NH + sb], ea2 * Ydec[4 * NH + db]);
    atomicAdd(&Mdec[5 * NH + sb], ea2 * Ydec[5 * NH + db]);
    atomicAdd(&Mdec[6 * NH + sb], ea2 * Ydec[6 * NH + db]);
    atomicAdd(&Mdec[7 * NH + sb], ea2 * Ydec[7 * NH + db]);
    atomicAdd(&Mdec[8 * NH + sb], ea2 * Ydec[8 * NH + db]);
}

// ---------------------------------------------------------------------------
// AB = M@Y + Y@M; t = (1+0.1q)*AB; Tdec = decompose(t)/(||t||^2+1)
__global__ __launch_bounds__(256) void k_abnorm(
        const float* __restrict__ Mdec, const float* __restrict__ Ydec,
        const float* __restrict__ q, float* __restrict__ Tdec) {
    int i = blockIdx.x * 256 + threadIdx.x;
    if (i >= NH) return;
    float md[9], yd[9];
#pragma unroll
    for (int c = 0; c < 9; c++) { md[c] = Mdec[c * NH + i]; yd[c] = Ydec[c * NH + i]; }
    float m[9], y[9];
    build_full(md, m);
    build_full(yd, y);
    float ab[9];
#pragma unroll
    for (int ii = 0; ii < 3; ii++)
#pragma unroll
        for (int jj = 0; jj < 3; jj++) {
            float s = 0.f;
#pragma unroll
            for (int kk = 0; kk < 3; kk++)
                s += m[ii * 3 + kk] * y[kk * 3 + jj] + y[ii * 3 + kk] * m[kk * 3 + jj];
            ab[ii * 3 + jj] = s;
        }
    float scale = 1.f + 0.1f * q[i >> 7];
    float nrm = 0.f;
#pragma unroll
    for (int j = 0; j < 9; j++) { ab[j] *= scale; nrm += ab[j] * ab[j]; }
    float inv = 1.f / (nrm + 1.f);
    float tr3 = (ab[0] + ab[4] + ab[8]) * (1.f / 3.f);
    Tdec[0 * NH + i] = tr3 * inv;
    Tdec[1 * NH + i] = 0.5f * (ab[1] - ab[3]) * inv;
    Tdec[2 * NH + i] = 0.5f * (ab[2] - ab[6]) * inv;
    Tdec[3 * NH + i] = 0.5f * (ab[5] - ab[7]) * inv;
    Tdec[4 * NH + i] = (ab[0] - tr3) * inv;
    Tdec[5 * NH + i] = 0.5f * (ab[1] + ab[3]) * inv;
    Tdec[6 * NH + i] = 0.5f * (ab[2] + ab[6]) * inv;
    Tdec[7 * NH + i] = (ab[4] - tr3) * inv;
    Tdec[8 * NH + i] = 0.5f * (ab[5] + ab[7]) * inv;
}

// ---------------------------------------------------------------------------
// Final: Xout = Xn + dX + (1+0.1q) * dX@dX
__global__ __launch_bounds__(256) void k_final(
        const float* __restrict__ dXdec, const float* __restrict__ Xn,
        const float* __restrict__ q, float* __restrict__ Xout) {
    int i = blockIdx.x * 256 + threadIdx.x;
    if (i >= NH) return;
    float dd[9];
#pragma unroll
    for (int c = 0; c < 9; c++) dd[c] = dXdec[c * NH + i];
    float dx[9];
    build_full(dd, dx);
    float scale = 1.f + 0.1f * q[i >> 7];
    float prod[9];
#pragma unroll
    for (int ii = 0; ii < 3; ii++)
#pragma unroll
        for (int jj = 0; jj < 3; jj++) {
            float s = 0.f;
#pragma unroll
            for (int kk = 0; kk < 3; kk++)
                s += dx[ii * 3 + kk] * dx[kk * 3 + jj];
            prod[ii * 3 + jj] = s;
        }
#pragma unroll
    for (int j = 0; j < 9; j++)
        Xout[(size_t)i * 9 + j] = Xn[(size_t)i * 9 + j] + dx[j] + scale * prod[j];
}

// ---------------------------------------------------------------------------
extern "C" void kernel_launch(void* const* d_in, const int* in_sizes, int n_in,
                              void* d_out, int out_size, void* d_ws, size_t ws_size,
                              hipStream_t stream) {
    const float* X          = (const float*)d_in[0];
    const float* edge_attr  = (const float*)d_in[1];
    const float* edge_weight= (const float*)d_in[2];
    const float* q          = (const float*)d_in[3];
    const float* Ws1        = (const float*)d_in[4];
    const float* bs1        = (const float*)d_in[5];
    const float* Ws2        = (const float*)d_in[6];
    const float* bs2        = (const float*)d_in[7];
    const float* Ws3        = (const float*)d_in[8];
    const float* bs3        = (const float*)d_in[9];
    const float* Wt         = (const float*)d_in[10];
    const int*   eidx       = (const int*)d_in[11];
    float* Xout = (float*)d_out;

    float* ws = (float*)d_ws;
    size_t nodeFloats = (size_t)NH * 9;

    // choose edge-chunk size so buffers fit the workspace
    size_t CE = NEDGES;
    while (CE > 2048 &&
           (4 * nodeFloats + CE * (128 + 256 + 384)) * sizeof(float) > ws_size)
        CE >>= 1;

    size_t off = 0;
    float* Xn   = ws + off; off += nodeFloats;
    float* D    = ws + off; off += nodeFloats;   // also Tdec
    float* Ydec = ws + off; off += nodeFloats;   // also dXdec
    float* Mdec = ws + off; off += nodeFloats;
    float* ea1  = ws + off; off += CE * 128;
    float* ea2  = ws + off; off += CE * 256;
    float* ea3  = ws + off; off += CE * 384;

    const float* Xin = X;
    for (int l = 0; l < 2; l++) {
        const float* W1 = Ws1 + (size_t)l * H * R;
        const float* b1 = bs1 + (size_t)l * H;
        const float* W2 = Ws2 + (size_t)l * 2 * H * H;
        const float* b2 = bs2 + (size_t)l * 2 * H;
        const float* W3 = Ws3 + (size_t)l * 3 * H * 2 * H;
        const float* b3 = bs3 + (size_t)l * 3 * H;
        const float* Wtl = Wt + (size_t)l * 6 * H * H;

        k_node_prep<<<NH / 256, 256, 0, stream>>>(Xin, Xn, D);
        k_gemm_mix<<<dim3(NATOMS / BM, H / BN, 9), 256, 0, stream>>>(D, Wtl, Ydec);
        hipMemsetAsync(Mdec, 0, nodeFloats * sizeof(float), stream);

        for (size_t e0 = 0; e0 < NEDGES; e0 += CE) {
            k_gemm<1><<<dim3(CE / BM, 128 / BN), 256, 0, stream>>>(
                edge_attr + e0 * R, W1, b1, nullptr, ea1, R, 128);
            k_gemm<1><<<dim3(CE / BM, 256 / BN), 256, 0, stream>>>(
                ea1, W2, b2, nullptr, ea2, 128, 256);
            k_gemm<2><<<dim3(CE / BM, 384 / BN), 256, 0, stream>>>(
                ea2, W3, b3, edge_weight + e0, ea3, 256, 384);
            k_scatter<<<(CE * H) / 256, 256, 0, stream>>>(
                ea3, eidx, Ydec, Mdec, (int)e0, (int)CE);
        }

        k_abnorm<<<NH / 256, 256, 0, stream>>>(Mdec, Ydec, q, D /*Tdec*/);
        k_gemm_mix<<<dim3(NATOMS / BM, H / BN, 9), 256, 0, stream>>>(
            D, Wtl + 3 * H * H, Ydec /*dXdec*/);
        k_final<<<NH / 256, 256, 0, stream>>>(Ydec, Xn, q, Xout);

        Xin = Xout;
    }
}

// Round 2
// 490.687 us; speedup vs baseline: 1.2666x; 1.2666x over previous
//
#include <hip/hip_runtime.h>
#include <math.h>

#define H 128
#define R 32
#define NATOMS 2048
#define NEDGES 32768
#define NH (NATOMS * H)          // 262144 (n,h) pairs
#define CUTOFF_F 4.5f
#define PI_OVER_CUTOFF 0.6981317007977318f

#define BM 64
#define BN 64
#define BK 32

// ---------------------------------------------------------------------------
__device__ __forceinline__ float silu_f(float x) {
    return x / (1.f + __expf(-x));
}

// Build full 3x3 from decomposition [i0, a01, a02, a12, s00, s01, s02, s11, s12]
__device__ __forceinline__ void build_full(const float d[9], float m[9]) {
    float i0 = d[0], a01 = d[1], a02 = d[2], a12 = d[3];
    float s00 = d[4], s01 = d[5], s02 = d[6], s11 = d[7], s12 = d[8];
    float s22 = -(s00 + s11);
    m[0] = i0 + s00;  m[1] = a01 + s01;  m[2] = a02 + s02;
    m[3] = s01 - a01; m[4] = i0 + s11;   m[5] = a12 + s12;
    m[6] = s02 - a02; m[7] = s12 - a12;  m[8] = i0 + s22;
}

// ---------------------------------------------------------------------------
// Node prep: X -> Xn (normalized, [nh][9]) and decomposition D (9 planes of NH)
__global__ __launch_bounds__(256) void k_node_prep(
        const float* __restrict__ X, float* __restrict__ Xn,
        float* __restrict__ D) {
    int i = blockIdx.x * 256 + threadIdx.x;
    if (i >= NH) return;
    const float* x = X + (size_t)i * 9;
    float v[9];
    float ss = 0.f;
#pragma unroll
    for (int j = 0; j < 9; j++) { v[j] = x[j]; ss += v[j] * v[j]; }
    float inv = 1.f / (ss + 1.f);
#pragma unroll
    for (int j = 0; j < 9; j++) { v[j] *= inv; Xn[(size_t)i * 9 + j] = v[j]; }
    float i0 = (v[0] + v[4] + v[8]) * (1.f / 3.f);
    D[0 * NH + i] = i0;
    D[1 * NH + i] = 0.5f * (v[1] - v[3]);
    D[2 * NH + i] = 0.5f * (v[2] - v[6]);
    D[3 * NH + i] = 0.5f * (v[5] - v[7]);
    D[4 * NH + i] = v[0] - i0;
    D[5 * NH + i] = 0.5f * (v[1] + v[3]);
    D[6 * NH + i] = 0.5f * (v[2] + v[6]);
    D[7 * NH + i] = v[4] - i0;
    D[8 * NH + i] = 0.5f * (v[5] + v[7]);
}

// ---------------------------------------------------------------------------
// Generic fp32 tile GEMM body: Out[m,n] = epilogue( sum_k A[m,k]*W[n,k] )
// MODE 0: plain; MODE 1: +bias, silu; MODE 2: +bias, silu, *cosine-cutoff(ew[m])
template <int MODE>
__device__ __forceinline__ void gemm_tile_body(
        const float* __restrict__ A, const float* __restrict__ W,
        const float* __restrict__ bias, const float* __restrict__ ew,
        float* __restrict__ Out, int K, int N, int m0, int n0) {
    __shared__ float As[BK][BM + 4];
    __shared__ float Bs[BK][BN + 4];
    int t = threadIdx.x;
    int tn = t & 15, tm = t >> 4;
    int r0 = tm * 4, c0 = tn * 4;
    float acc[4][4];
#pragma unroll
    for (int i = 0; i < 4; i++)
#pragma unroll
        for (int j = 0; j < 4; j++) acc[i][j] = 0.f;

    for (int k0 = 0; k0 < K; k0 += BK) {
#pragma unroll
        for (int i = 0; i < 2; i++) {
            int idx = t * 2 + i;          // 0..511 float4 slots
            int m = idx >> 3, k4 = idx & 7;
            float4 va = *(const float4*)&A[(size_t)(m0 + m) * K + k0 + k4 * 4];
            As[k4 * 4 + 0][m] = va.x; As[k4 * 4 + 1][m] = va.y;
            As[k4 * 4 + 2][m] = va.z; As[k4 * 4 + 3][m] = va.w;
            float4 vb = *(const float4*)&W[(size_t)(n0 + m) * K + k0 + k4 * 4];
            Bs[k4 * 4 + 0][m] = vb.x; Bs[k4 * 4 + 1][m] = vb.y;
            Bs[k4 * 4 + 2][m] = vb.z; Bs[k4 * 4 + 3][m] = vb.w;
        }
        __syncthreads();
#pragma unroll
        for (int kk = 0; kk < BK; kk++) {
            float4 a4 = *(const float4*)&As[kk][r0];
            float4 b4 = *(const float4*)&Bs[kk][c0];
            float av[4] = {a4.x, a4.y, a4.z, a4.w};
            float bv[4] = {b4.x, b4.y, b4.z, b4.w};
#pragma unroll
            for (int i = 0; i < 4; i++)
#pragma unroll
                for (int j = 0; j < 4; j++)
                    acc[i][j] = fmaf(av[i], bv[j], acc[i][j]);
        }
        __syncthreads();
    }

    float bb[4] = {0.f, 0.f, 0.f, 0.f};
    if (MODE >= 1) {
        bb[0] = bias[n0 + c0];     bb[1] = bias[n0 + c0 + 1];
        bb[2] = bias[n0 + c0 + 2]; bb[3] = bias[n0 + c0 + 3];
    }
    float cs[4] = {1.f, 1.f, 1.f, 1.f};
    if (MODE == 2) {
#pragma unroll
        for (int i = 0; i < 4; i++) {
            float w = ew[m0 + r0 + i];
            cs[i] = (w < CUTOFF_F) ? 0.5f * (__cosf(w * PI_OVER_CUTOFF) + 1.f) : 0.f;
        }
    }
#pragma unroll
    for (int i = 0; i < 4; i++) {
        float4 o;
        float* op = &o.x;
#pragma unroll
        for (int j = 0; j < 4; j++) {
            float x = acc[i][j];
            if (MODE >= 1) { x += bb[j]; x = silu_f(x); }
            if (MODE == 2) { x *= cs[i]; }
            op[j] = x;
        }
        *(float4*)&Out[(size_t)(m0 + r0 + i) * N + n0 + c0] = o;
    }
}

template <int MODE>
__global__ __launch_bounds__(256) void k_gemm(
        const float* __restrict__ A, const float* __restrict__ W,
        const float* __restrict__ bias, const float* __restrict__ ew,
        float* __restrict__ Out, int K, int N) {
    gemm_tile_body<MODE>(A, W, bias, ew, Out, K, N,
                         blockIdx.x * BM, blockIdx.y * BN);
}

// Channel-mix batched GEMM: 9 component planes; plane c uses Wt part (0|1|2)
__global__ __launch_bounds__(256) void k_gemm_mix(
        const float* __restrict__ Din, const float* __restrict__ Wtbase,
        float* __restrict__ Outp) {
    int c = blockIdx.z;
    int part = (c == 0) ? 0 : ((c < 4) ? 1 : 2);
    gemm_tile_body<0>(Din + (size_t)c * NH, Wtbase + part * H * H,
                      nullptr, nullptr, Outp + (size_t)c * NH,
                      H, H, blockIdx.x * BM, blockIdx.y * BN);
}

// ---------------------------------------------------------------------------
// CSR build over an edge chunk (src = eidx[e0..e0+nE))
__global__ __launch_bounds__(256) void k_hist(
        const int* __restrict__ eidx, int e0, int nE, int* __restrict__ cnt) {
    int e = blockIdx.x * 256 + threadIdx.x;
    if (e < nE) atomicAdd(&cnt[eidx[e0 + e]], 1);
}

// exclusive scan of cnt[0..2047] -> rowstart[0..2048], cursor copy
__global__ __launch_bounds__(256) void k_scan(
        const int* __restrict__ cnt, int* __restrict__ rowstart,
        int* __restrict__ cursor) {
    __shared__ int partial[256];
    int t = threadIdx.x;
    int loc[8];
    int run = 0;
#pragma unroll
    for (int j = 0; j < 8; j++) {
        int v = cnt[t * 8 + j];
        loc[j] = run; run += v;
    }
    partial[t] = run;
    __syncthreads();
    if (t == 0) {
        int acc = 0;
        for (int i = 0; i < 256; i++) { int v = partial[i]; partial[i] = acc; acc += v; }
        rowstart[2048] = acc;
    }
    __syncthreads();
    int base = partial[t];
#pragma unroll
    for (int j = 0; j < 8; j++) {
        rowstart[t * 8 + j] = base + loc[j];
        cursor[t * 8 + j] = base + loc[j];
    }
}

__global__ __launch_bounds__(256) void k_fill(
        const int* __restrict__ eidx, int e0, int nE,
        int* __restrict__ cursor, int* __restrict__ elist) {
    int e = blockIdx.x * 256 + threadIdx.x;
    if (e >= nE) return;
    int src = eidx[e0 + e];
    int pos = atomicAdd(&cursor[src], 1);
    elist[pos] = e;   // chunk-local edge id
}

// ---------------------------------------------------------------------------
// Gather: Mdec[n,h] += sum over edges e with src==n of ea[e,h,:] .* Ydec[dst,h]
// (decomposed 9 comps; accumulates on top of existing Mdec -> supports chunks)
__global__ __launch_bounds__(256) void k_gather(
        const float* __restrict__ ea, const int* __restrict__ eidx,
        const int* __restrict__ rowstart, const int* __restrict__ elist,
        const float* __restrict__ Ydec, float* __restrict__ Mdec, int e0) {
    int gid = blockIdx.x * 256 + threadIdx.x;   // NH threads, n = gid>>7
    int n = gid >> 7;
    int h = gid & 127;
    int beg = rowstart[n], end = rowstart[n + 1];
    float acc[9];
#pragma unroll
    for (int c = 0; c < 9; c++) acc[c] = Mdec[c * NH + gid];
    for (int idx = beg; idx < end; ++idx) {
        int e = elist[idx];
        int dst = eidx[NEDGES + e0 + e];
        const float* eap = ea + (size_t)e * 384 + h * 3;
        float e0v = eap[0], e1v = eap[1], e2v = eap[2];
        int db = dst * H + h;
        acc[0] += e0v * Ydec[0 * NH + db];
        acc[1] += e1v * Ydec[1 * NH + db];
        acc[2] += e1v * Ydec[2 * NH + db];
        acc[3] += e1v * Ydec[3 * NH + db];
#pragma unroll
        for (int c = 4; c < 9; c++) acc[c] += e2v * Ydec[c * NH + db];
    }
#pragma unroll
    for (int c = 0; c < 9; c++) Mdec[c * NH + gid] = acc[c];
}

// ---------------------------------------------------------------------------
// AB = M@Y + Y@M; t = (1+0.1q)*AB; Tdec = decompose(t)/(||t||^2+1)
__global__ __launch_bounds__(256) void k_abnorm(
        const float* __restrict__ Mdec, const float* __restrict__ Ydec,
        const float* __restrict__ q, float* __restrict__ Tdec) {
    int i = blockIdx.x * 256 + threadIdx.x;
    if (i >= NH) return;
    float md[9], yd[9];
#pragma unroll
    for (int c = 0; c < 9; c++) { md[c] = Mdec[c * NH + i]; yd[c] = Ydec[c * NH + i]; }
    float m[9], y[9];
    build_full(md, m);
    build_full(yd, y);
    float ab[9];
#pragma unroll
    for (int ii = 0; ii < 3; ii++)
#pragma unroll
        for (int jj = 0; jj < 3; jj++) {
            float s = 0.f;
#pragma unroll
            for (int kk = 0; kk < 3; kk++)
                s += m[ii * 3 + kk] * y[kk * 3 + jj] + y[ii * 3 + kk] * m[kk * 3 + jj];
            ab[ii * 3 + jj] = s;
        }
    float scale = 1.f + 0.1f * q[i >> 7];
    float nrm = 0.f;
#pragma unroll
    for (int j = 0; j < 9; j++) { ab[j] *= scale; nrm += ab[j] * ab[j]; }
    float inv = 1.f / (nrm + 1.f);
    float tr3 = (ab[0] + ab[4] + ab[8]) * (1.f / 3.f);
    Tdec[0 * NH + i] = tr3 * inv;
    Tdec[1 * NH + i] = 0.5f * (ab[1] - ab[3]) * inv;
    Tdec[2 * NH + i] = 0.5f * (ab[2] - ab[6]) * inv;
    Tdec[3 * NH + i] = 0.5f * (ab[5] - ab[7]) * inv;
    Tdec[4 * NH + i] = (ab[0] - tr3) * inv;
    Tdec[5 * NH + i] = 0.5f * (ab[1] + ab[3]) * inv;
    Tdec[6 * NH + i] = 0.5f * (ab[2] + ab[6]) * inv;
    Tdec[7 * NH + i] = (ab[4] - tr3) * inv;
    Tdec[8 * NH + i] = 0.5f * (ab[5] + ab[7]) * inv;
}

// ---------------------------------------------------------------------------
// Final: Xout = Xn + dX + (1+0.1q) * dX@dX
__global__ __launch_bounds__(256) void k_final(
        const float* __restrict__ dXdec, const float* __restrict__ Xn,
        const float* __restrict__ q, float* __restrict__ Xout) {
    int i = blockIdx.x * 256 + threadIdx.x;
    if (i >= NH) return;
    float dd[9];
#pragma unroll
    for (int c = 0; c < 9; c++) dd[c] = dXdec[c * NH + i];
    float dx[9];
    build_full(dd, dx);
    float scale = 1.f + 0.1f * q[i >> 7];
    float prod[9];
#pragma unroll
    for (int ii = 0; ii < 3; ii++)
#pragma unroll
        for (int jj = 0; jj < 3; jj++) {
            float s = 0.f;
#pragma unroll
            for (int kk = 0; kk < 3; kk++)
                s += dx[ii * 3 + kk] * dx[kk * 3 + jj];
            prod[ii * 3 + jj] = s;
        }
#pragma unroll
    for (int j = 0; j < 9; j++)
        Xout[(size_t)i * 9 + j] = Xn[(size_t)i * 9 + j] + dx[j] + scale * prod[j];
}

// ---------------------------------------------------------------------------
extern "C" void kernel_launch(void* const* d_in, const int* in_sizes, int n_in,
                              void* d_out, int out_size, void* d_ws, size_t ws_size,
                              hipStream_t stream) {
    const float* X          = (const float*)d_in[0];
    const float* edge_attr  = (const float*)d_in[1];
    const float* edge_weight= (const float*)d_in[2];
    const float* q          = (const float*)d_in[3];
    const float* Ws1        = (const float*)d_in[4];
    const float* bs1        = (const float*)d_in[5];
    const float* Ws2        = (const float*)d_in[6];
    const float* bs2        = (const float*)d_in[7];
    const float* Ws3        = (const float*)d_in[8];
    const float* bs3        = (const float*)d_in[9];
    const float* Wt         = (const float*)d_in[10];
    const int*   eidx       = (const int*)d_in[11];
    float* Xout = (float*)d_out;

    float* ws = (float*)d_ws;
    size_t nodeFloats = (size_t)NH * 9;

    // choose edge-chunk size so buffers fit the workspace
    // floats: 4 node bufs + CE*(128+256+384); ints: 2048+2049+2048+CE
    size_t CE = NEDGES;
    while (CE > 2048 &&
           (4 * nodeFloats + CE * (128 + 256 + 384) + (6145 + CE) + 64) * sizeof(float)
               > ws_size)
        CE >>= 1;

    size_t off = 0;
    float* Xn   = ws + off; off += nodeFloats;
    float* D    = ws + off; off += nodeFloats;   // also Tdec
    float* Ydec = ws + off; off += nodeFloats;   // also dXdec
    float* Mdec = ws + off; off += nodeFloats;
    float* ea1  = ws + off; off += CE * 128;
    float* ea2  = ws + off; off += CE * 256;
    float* ea3  = ws + off; off += CE * 384;
    int* ibase    = (int*)(ws + off);
    int* cnt      = ibase;              // 2048
    int* rowstart = ibase + 2048;       // 2049
    int* cursor   = ibase + 2048 + 2049;// 2048
    int* elist    = ibase + 2048 + 2049 + 2048; // CE

    const float* Xin = X;
    for (int l = 0; l < 2; l++) {
        const float* W1 = Ws1 + (size_t)l * H * R;
        const float* b1 = bs1 + (size_t)l * H;
        const float* W2 = Ws2 + (size_t)l * 2 * H * H;
        const float* b2 = bs2 + (size_t)l * 2 * H;
        const float* W3 = Ws3 + (size_t)l * 3 * H * 2 * H;
        const float* b3 = bs3 + (size_t)l * 3 * H;
        const float* Wtl = Wt + (size_t)l * 6 * H * H;

        k_node_prep<<<NH / 256, 256, 0, stream>>>(Xin, Xn, D);
        k_gemm_mix<<<dim3(NATOMS / BM, H / BN, 9), 256, 0, stream>>>(D, Wtl, Ydec);
        hipMemsetAsync(Mdec, 0, nodeFloats * sizeof(float), stream);

        for (size_t e0 = 0; e0 < NEDGES; e0 += CE) {
            // edge MLP on the chunk
            k_gemm<1><<<dim3(CE / BM, 128 / BN), 256, 0, stream>>>(
                edge_attr + e0 * R, W1, b1, nullptr, ea1, R, 128);
            k_gemm<1><<<dim3(CE / BM, 256 / BN), 256, 0, stream>>>(
                ea1, W2, b2, nullptr, ea2, 128, 256);
            k_gemm<2><<<dim3(CE / BM, 384 / BN), 256, 0, stream>>>(
                ea2, W3, b3, edge_weight + e0, ea3, 256, 384);
            // CSR build for this chunk, then gather-accumulate
            hipMemsetAsync(cnt, 0, 2048 * sizeof(int), stream);
            k_hist<<<(CE + 255) / 256, 256, 0, stream>>>(eidx, (int)e0, (int)CE, cnt);
            k_scan<<<1, 256, 0, stream>>>(cnt, rowstart, cursor);
            k_fill<<<(CE + 255) / 256, 256, 0, stream>>>(eidx, (int)e0, (int)CE, cursor, elist);
            k_gather<<<NH / 256, 256, 0, stream>>>(
                ea3, eidx, rowstart, elist, Ydec, Mdec, (int)e0);
        }

        k_abnorm<<<NH / 256, 256, 0, stream>>>(Mdec, Ydec, q, D /*Tdec*/);
        k_gemm_mix<<<dim3(NATOMS / BM, H / BN, 9), 256, 0, stream>>>(
            D, Wtl + 3 * H * H, Ydec /*dXdec*/);
        k_final<<<NH / 256, 256, 0, stream>>>(Ydec, Xn, q, Xout);

        Xin = Xout;
    }
}

// Round 3
// 289.561 us; speedup vs baseline: 2.1464x; 1.6946x over previous
//
#include <hip/hip_runtime.h>
#include <hip/hip_bf16.h>
#include <math.h>

#define H 128
#define R 32
#define NATOMS 2048
#define NEDGES 32768
#define NH (NATOMS * H)          // 262144 (n,h) pairs
#define CUTOFF_F 4.5f
#define PI_OVER_CUTOFF 0.6981317007977318f

#define BM 64
#define BN 64
#define BK 32

typedef __bf16 bf16x8 __attribute__((ext_vector_type(8)));
typedef float f32x4 __attribute__((ext_vector_type(4)));
typedef short short8 __attribute__((ext_vector_type(8)));

// ---------------------------------------------------------------------------
__device__ __forceinline__ float silu_f(float x) {
    return x / (1.f + __expf(-x));
}

// Build full 3x3 from decomposition [i0, a01, a02, a12, s00, s01, s02, s11, s12]
__device__ __forceinline__ void build_full(const float d[9], float m[9]) {
    float i0 = d[0], a01 = d[1], a02 = d[2], a12 = d[3];
    float s00 = d[4], s01 = d[5], s02 = d[6], s11 = d[7], s12 = d[8];
    float s22 = -(s00 + s11);
    m[0] = i0 + s00;  m[1] = a01 + s01;  m[2] = a02 + s02;
    m[3] = s01 - a01; m[4] = i0 + s11;   m[5] = a12 + s12;
    m[6] = s02 - a02; m[7] = s12 - a12;  m[8] = i0 + s22;
}

// ---------------------------------------------------------------------------
// fp32 -> bf16 cast
__global__ __launch_bounds__(256) void k_f2b(
        const float* __restrict__ in, __hip_bfloat16* __restrict__ out, int n) {
    int i = blockIdx.x * 256 + threadIdx.x;
    if (i < n) out[i] = __float2bfloat16(in[i]);
}

// ---------------------------------------------------------------------------
// Node prep: X -> Xn (normalized, [nh][9]) and decomposition D (9 planes of NH)
__global__ __launch_bounds__(256) void k_node_prep(
        const float* __restrict__ X, float* __restrict__ Xn,
        float* __restrict__ D) {
    int i = blockIdx.x * 256 + threadIdx.x;
    if (i >= NH) return;
    const float* x = X + (size_t)i * 9;
    float v[9];
    float ss = 0.f;
#pragma unroll
    for (int j = 0; j < 9; j++) { v[j] = x[j]; ss += v[j] * v[j]; }
    float inv = 1.f / (ss + 1.f);
#pragma unroll
    for (int j = 0; j < 9; j++) { v[j] *= inv; Xn[(size_t)i * 9 + j] = v[j]; }
    float i0 = (v[0] + v[4] + v[8]) * (1.f / 3.f);
    D[0 * NH + i] = i0;
    D[1 * NH + i] = 0.5f * (v[1] - v[3]);
    D[2 * NH + i] = 0.5f * (v[2] - v[6]);
    D[3 * NH + i] = 0.5f * (v[5] - v[7]);
    D[4 * NH + i] = v[0] - i0;
    D[5 * NH + i] = 0.5f * (v[1] + v[3]);
    D[6 * NH + i] = 0.5f * (v[2] + v[6]);
    D[7 * NH + i] = v[4] - i0;
    D[8 * NH + i] = 0.5f * (v[5] + v[7]);
}

// ---------------------------------------------------------------------------
// fp32 tile GEMM (kept for the channel-mix): Out[m,n] = sum_k A[m,k]*W[n,k]
__device__ __forceinline__ void gemm_tile_body_f32(
        const float* __restrict__ A, const float* __restrict__ W,
        float* __restrict__ Out, int K, int N, int m0, int n0) {
    __shared__ float As[BK][BM + 4];
    __shared__ float Bs[BK][BN + 4];
    int t = threadIdx.x;
    int tn = t & 15, tm = t >> 4;
    int r0 = tm * 4, c0 = tn * 4;
    float acc[4][4];
#pragma unroll
    for (int i = 0; i < 4; i++)
#pragma unroll
        for (int j = 0; j < 4; j++) acc[i][j] = 0.f;

    for (int k0 = 0; k0 < K; k0 += BK) {
#pragma unroll
        for (int i = 0; i < 2; i++) {
            int idx = t * 2 + i;          // 0..511 float4 slots
            int m = idx >> 3, k4 = idx & 7;
            float4 va = *(const float4*)&A[(size_t)(m0 + m) * K + k0 + k4 * 4];
            As[k4 * 4 + 0][m] = va.x; As[k4 * 4 + 1][m] = va.y;
            As[k4 * 4 + 2][m] = va.z; As[k4 * 4 + 3][m] = va.w;
            float4 vb = *(const float4*)&W[(size_t)(n0 + m) * K + k0 + k4 * 4];
            Bs[k4 * 4 + 0][m] = vb.x; Bs[k4 * 4 + 1][m] = vb.y;
            Bs[k4 * 4 + 2][m] = vb.z; Bs[k4 * 4 + 3][m] = vb.w;
        }
        __syncthreads();
#pragma unroll
        for (int kk = 0; kk < BK; kk++) {
            float4 a4 = *(const float4*)&As[kk][r0];
            float4 b4 = *(const float4*)&Bs[kk][c0];
            float av[4] = {a4.x, a4.y, a4.z, a4.w};
            float bv[4] = {b4.x, b4.y, b4.z, b4.w};
#pragma unroll
            for (int i = 0; i < 4; i++)
#pragma unroll
                for (int j = 0; j < 4; j++)
                    acc[i][j] = fmaf(av[i], bv[j], acc[i][j]);
        }
        __syncthreads();
    }
#pragma unroll
    for (int i = 0; i < 4; i++) {
        float4 o;
        o.x = acc[i][0]; o.y = acc[i][1]; o.z = acc[i][2]; o.w = acc[i][3];
        *(float4*)&Out[(size_t)(m0 + r0 + i) * N + n0 + c0] = o;
    }
}

// Channel-mix batched GEMM: 9 component planes; plane c uses Wt part (0|1|2)
__global__ __launch_bounds__(256) void k_gemm_mix(
        const float* __restrict__ Din, const float* __restrict__ Wtbase,
        float* __restrict__ Outp) {
    int c = blockIdx.z;
    int part = (c == 0) ? 0 : ((c < 4) ? 1 : 2);
    gemm_tile_body_f32(Din + (size_t)c * NH, Wtbase + part * H * H,
                       Outp + (size_t)c * NH,
                       H, H, blockIdx.x * BM, blockIdx.y * BN);
}

// ---------------------------------------------------------------------------
// bf16 MFMA GEMM for the edge MLP.  Out[m,n] = epi( sum_k A[m,k]*W[n,k] )
// A:[M,K] bf16 row-major, W:[N,K] bf16 row-major. 128x64 tile, 4 waves,
// double-buffered LDS via global_load_lds(16B) with XOR-swizzled layout
// (linear LDS dest + pre-swizzled global source + swizzled ds_read — rule #21).
// MODE 1: +bias, silu ; MODE 2: +bias, silu, *cosine-cutoff(ew[m])
template <int K, int N, int MODE>
__global__ __launch_bounds__(256) void k_mlp(
        const __hip_bfloat16* __restrict__ A, const __hip_bfloat16* __restrict__ W,
        const float* __restrict__ bias, const float* __restrict__ ew,
        __hip_bfloat16* __restrict__ Out) {
    constexpr int BKm = (K >= 64) ? 64 : 32;   // K-step
    constexpr int RB  = BKm * 2;               // row bytes in LDS tile
    constexpr int SWZ = (BKm == 64) ? 7 : 3;   // row-XOR mask over 16B slots
    constexpr int NIT = K / BKm;
    constexpr int ABYTES = 128 * RB;
    constexpr int BBYTES = 64 * RB;
    constexpr int AISS = ABYTES / 1024 / 4;    // 1KB issues per wave (A)
    constexpr int BISS = BBYTES / 1024 / 4;

    __shared__ char lds[2][ABYTES + BBYTES];

    const int t = threadIdx.x;
    const int lane = t & 63;
    const int w = t >> 6;
    const int wm = (w & 1) * 64;     // wave m-offset in tile
    const int wn = (w >> 1) * 32;    // wave n-offset in tile
    const int m0 = blockIdx.x * 128;
    const int n0 = blockIdx.y * 64;

    f32x4 acc[4][2] = {};

    auto stage = [&](int b, int it) {
        const int k0 = it * BKm;
        char* As = lds[b];
        char* Bs = lds[b] + ABYTES;
#pragma unroll
        for (int i = 0; i < AISS; i++) {
            int base = (w * AISS + i) * 1024;
            int lin = base + lane * 16;
            int row = lin / RB;
            int slot = (lin % RB) >> 4;
            int sl = slot ^ (row & SWZ);   // pre-swizzle the SOURCE
            const char* src = (const char*)(A + (size_t)(m0 + row) * K + k0) + sl * 16;
            __builtin_amdgcn_global_load_lds(
                (const __attribute__((address_space(1))) void*)src,
                (__attribute__((address_space(3))) void*)(As + base), 16, 0, 0);
        }
#pragma unroll
        for (int i = 0; i < BISS; i++) {
            int base = (w * BISS + i) * 1024;
            int lin = base + lane * 16;
            int row = lin / RB;
            int slot = (lin % RB) >> 4;
            int sl = slot ^ (row & SWZ);
            const char* src = (const char*)(W + (size_t)(n0 + row) * K + k0) + sl * 16;
            __builtin_amdgcn_global_load_lds(
                (const __attribute__((address_space(1))) void*)src,
                (__attribute__((address_space(3))) void*)(Bs + base), 16, 0, 0);
        }
    };

    auto compute = [&](int b) {
        const char* As = lds[b];
        const char* Bs = lds[b] + ABYTES;
        const int rA = wm + (lane & 15);
        const int rB = wn + (lane & 15);
        const int c = lane >> 4;           // 16B k-chunk index
#pragma unroll
        for (int kk = 0; kk < BKm / 32; kk++) {
            bf16x8 av[4], bv[2];
#pragma unroll
            for (int mf = 0; mf < 4; mf++) {
                int row = rA + mf * 16;
                int sp = (kk * 4 + c) ^ (row & SWZ);
                av[mf] = __builtin_bit_cast(bf16x8,
                    *(const short8*)(As + row * RB + sp * 16));
            }
#pragma unroll
            for (int nf = 0; nf < 2; nf++) {
                int row = rB + nf * 16;
                int sp = (kk * 4 + c) ^ (row & SWZ);
                bv[nf] = __builtin_bit_cast(bf16x8,
                    *(const short8*)(Bs + row * RB + sp * 16));
            }
#pragma unroll
            for (int mf = 0; mf < 4; mf++)
#pragma unroll
                for (int nf = 0; nf < 2; nf++)
                    acc[mf][nf] = __builtin_amdgcn_mfma_f32_16x16x32_bf16(
                        av[mf], bv[nf], acc[mf][nf], 0, 0, 0);
        }
    };

    stage(0, 0);
    asm volatile("s_waitcnt vmcnt(0)" ::: "memory");
    __syncthreads();
    for (int it = 0; it < NIT; it++) {
        int b = it & 1;
        if (it + 1 < NIT) stage(b ^ 1, it + 1);
        compute(b);
        asm volatile("s_waitcnt vmcnt(0)" ::: "memory");
        __syncthreads();
    }

    // epilogue: C/D layout col=lane&15, row=(lane>>4)*4+reg  [m89/m91]
#pragma unroll
    for (int mf = 0; mf < 4; mf++) {
#pragma unroll
        for (int r = 0; r < 4; r++) {
            int row = m0 + wm + mf * 16 + (lane >> 4) * 4 + r;
            float cs = 1.f;
            if (MODE == 2) {
                float wv = ew[row];
                cs = (wv < CUTOFF_F) ? 0.5f * (__cosf(wv * PI_OVER_CUTOFF) + 1.f) : 0.f;
            }
#pragma unroll
            for (int nf = 0; nf < 2; nf++) {
                int col = n0 + wn + nf * 16 + (lane & 15);
                float x = acc[mf][nf][r];
                x += bias[col];
                x = silu_f(x);
                if (MODE == 2) x *= cs;
                Out[(size_t)row * N + col] = __float2bfloat16(x);
            }
        }
    }
}

// ---------------------------------------------------------------------------
// CSR build over an edge chunk (src = eidx[e0..e0+nE))
__global__ __launch_bounds__(256) void k_hist(
        const int* __restrict__ eidx, int e0, int nE, int* __restrict__ cnt) {
    int e = blockIdx.x * 256 + threadIdx.x;
    if (e < nE) atomicAdd(&cnt[eidx[e0 + e]], 1);
}

__global__ __launch_bounds__(256) void k_scan(
        const int* __restrict__ cnt, int* __restrict__ rowstart,
        int* __restrict__ cursor) {
    __shared__ int partial[256];
    int t = threadIdx.x;
    int loc[8];
    int run = 0;
#pragma unroll
    for (int j = 0; j < 8; j++) {
        int v = cnt[t * 8 + j];
        loc[j] = run; run += v;
    }
    partial[t] = run;
    __syncthreads();
    if (t == 0) {
        int acc = 0;
        for (int i = 0; i < 256; i++) { int v = partial[i]; partial[i] = acc; acc += v; }
        rowstart[2048] = acc;
    }
    __syncthreads();
    int base = partial[t];
#pragma unroll
    for (int j = 0; j < 8; j++) {
        rowstart[t * 8 + j] = base + loc[j];
        cursor[t * 8 + j] = base + loc[j];
    }
}

__global__ __launch_bounds__(256) void k_fill(
        const int* __restrict__ eidx, int e0, int nE,
        int* __restrict__ cursor, int* __restrict__ elist) {
    int e = blockIdx.x * 256 + threadIdx.x;
    if (e >= nE) return;
    int src = eidx[e0 + e];
    int pos = atomicAdd(&cursor[src], 1);
    elist[pos] = e;   // chunk-local edge id
}

// ---------------------------------------------------------------------------
// Gather: Mdec[n,h] += sum over edges e with src==n of ea[e,h,:] .* Ydec[dst,h]
__global__ __launch_bounds__(256) void k_gather(
        const __hip_bfloat16* __restrict__ ea, const int* __restrict__ eidx,
        const int* __restrict__ rowstart, const int* __restrict__ elist,
        const float* __restrict__ Ydec, float* __restrict__ Mdec, int e0) {
    int gid = blockIdx.x * 256 + threadIdx.x;   // NH threads, n = gid>>7
    int n = gid >> 7;
    int h = gid & 127;
    int beg = rowstart[n], end = rowstart[n + 1];
    float acc[9];
#pragma unroll
    for (int c = 0; c < 9; c++) acc[c] = Mdec[c * NH + gid];
    for (int idx = beg; idx < end; ++idx) {
        int e = elist[idx];
        int dst = eidx[NEDGES + e0 + e];
        const __hip_bfloat16* eap = ea + (size_t)e * 384 + h * 3;
        float e0v = __bfloat162float(eap[0]);
        float e1v = __bfloat162float(eap[1]);
        float e2v = __bfloat162float(eap[2]);
        int db = dst * H + h;
        acc[0] += e0v * Ydec[0 * NH + db];
        acc[1] += e1v * Ydec[1 * NH + db];
        acc[2] += e1v * Ydec[2 * NH + db];
        acc[3] += e1v * Ydec[3 * NH + db];
#pragma unroll
        for (int c = 4; c < 9; c++) acc[c] += e2v * Ydec[c * NH + db];
    }
#pragma unroll
    for (int c = 0; c < 9; c++) Mdec[c * NH + gid] = acc[c];
}

// ---------------------------------------------------------------------------
// AB = M@Y + Y@M; t = (1+0.1q)*AB; Tdec = decompose(t)/(||t||^2+1)
__global__ __launch_bounds__(256) void k_abnorm(
        const float* __restrict__ Mdec, const float* __restrict__ Ydec,
        const float* __restrict__ q, float* __restrict__ Tdec) {
    int i = blockIdx.x * 256 + threadIdx.x;
    if (i >= NH) return;
    float md[9], yd[9];
#pragma unroll
    for (int c = 0; c < 9; c++) { md[c] = Mdec[c * NH + i]; yd[c] = Ydec[c * NH + i]; }
    float m[9], y[9];
    build_full(md, m);
    build_full(yd, y);
    float ab[9];
#pragma unroll
    for (int ii = 0; ii < 3; ii++)
#pragma unroll
        for (int jj = 0; jj < 3; jj++) {
            float s = 0.f;
#pragma unroll
            for (int kk = 0; kk < 3; kk++)
                s += m[ii * 3 + kk] * y[kk * 3 + jj] + y[ii * 3 + kk] * m[kk * 3 + jj];
            ab[ii * 3 + jj] = s;
        }
    float scale = 1.f + 0.1f * q[i >> 7];
    float nrm = 0.f;
#pragma unroll
    for (int j = 0; j < 9; j++) { ab[j] *= scale; nrm += ab[j] * ab[j]; }
    float inv = 1.f / (nrm + 1.f);
    float tr3 = (ab[0] + ab[4] + ab[8]) * (1.f / 3.f);
    Tdec[0 * NH + i] = tr3 * inv;
    Tdec[1 * NH + i] = 0.5f * (ab[1] - ab[3]) * inv;
    Tdec[2 * NH + i] = 0.5f * (ab[2] - ab[6]) * inv;
    Tdec[3 * NH + i] = 0.5f * (ab[5] - ab[7]) * inv;
    Tdec[4 * NH + i] = (ab[0] - tr3) * inv;
    Tdec[5 * NH + i] = 0.5f * (ab[1] + ab[3]) * inv;
    Tdec[6 * NH + i] = 0.5f * (ab[2] + ab[6]) * inv;
    Tdec[7 * NH + i] = (ab[4] - tr3) * inv;
    Tdec[8 * NH + i] = 0.5f * (ab[5] + ab[7]) * inv;
}

// ---------------------------------------------------------------------------
// Final: Xout = Xn + dX + (1+0.1q) * dX@dX
__global__ __launch_bounds__(256) void k_final(
        const float* __restrict__ dXdec, const float* __restrict__ Xn,
        const float* __restrict__ q, float* __restrict__ Xout) {
    int i = blockIdx.x * 256 + threadIdx.x;
    if (i >= NH) return;
    float dd[9];
#pragma unroll
    for (int c = 0; c < 9; c++) dd[c] = dXdec[c * NH + i];
    float dx[9];
    build_full(dd, dx);
    float scale = 1.f + 0.1f * q[i >> 7];
    float prod[9];
#pragma unroll
    for (int ii = 0; ii < 3; ii++)
#pragma unroll
        for (int jj = 0; jj < 3; jj++) {
            float s = 0.f;
#pragma unroll
            for (int kk = 0; kk < 3; kk++)
                s += dx[ii * 3 + kk] * dx[kk * 3 + jj];
            prod[ii * 3 + jj] = s;
        }
#pragma unroll
    for (int j = 0; j < 9; j++)
        Xout[(size_t)i * 9 + j] = Xn[(size_t)i * 9 + j] + dx[j] + scale * prod[j];
}

// ---------------------------------------------------------------------------
extern "C" void kernel_launch(void* const* d_in, const int* in_sizes, int n_in,
                              void* d_out, int out_size, void* d_ws, size_t ws_size,
                              hipStream_t stream) {
    const float* X          = (const float*)d_in[0];
    const float* edge_attr  = (const float*)d_in[1];
    const float* edge_weight= (const float*)d_in[2];
    const float* q          = (const float*)d_in[3];
    const float* Ws1        = (const float*)d_in[4];
    const float* bs1        = (const float*)d_in[5];
    const float* Ws2        = (const float*)d_in[6];
    const float* bs2        = (const float*)d_in[7];
    const float* Ws3        = (const float*)d_in[8];
    const float* bs3        = (const float*)d_in[9];
    const float* Wt         = (const float*)d_in[10];
    const int*   eidx       = (const int*)d_in[11];
    float* Xout = (float*)d_out;

    size_t nodeBytes = (size_t)NH * 9 * sizeof(float);

    // edge-chunk size so buffers fit the workspace (bytes)
    size_t CE = NEDGES;
    auto need = [&](size_t ce) -> size_t {
        size_t b = 4 * nodeBytes;                 // Xn, D, Ydec, Mdec
        b += (size_t)NEDGES * 32 * 2;             // edge_attr bf16
        b += (2 * 4096 + 2 * 32768 + 2 * 98304) * 2;  // W1b/W2b/W3b both layers
        b += ce * (128 + 256 + 384) * 2;          // ea1/ea2/ea3 bf16
        b += (2048 + 2049 + 2048 + ce) * 4;       // CSR ints
        b += 16 * 256;                            // alignment slack
        return b;
    };
    while (CE > 2048 && need(CE) > ws_size) CE >>= 1;

    char* p = (char*)d_ws;
    auto alloc = [&](size_t bytes) -> char* {
        char* r = p; p += (bytes + 255) & ~(size_t)255; return r;
    };
    float* Xn   = (float*)alloc(nodeBytes);
    float* D    = (float*)alloc(nodeBytes);   // also Tdec
    float* Ydec = (float*)alloc(nodeBytes);   // also dXdec
    float* Mdec = (float*)alloc(nodeBytes);
    __hip_bfloat16* eaB = (__hip_bfloat16*)alloc((size_t)NEDGES * 32 * 2);
    __hip_bfloat16* W1b = (__hip_bfloat16*)alloc(2 * 4096 * 2);
    __hip_bfloat16* W2b = (__hip_bfloat16*)alloc(2 * 32768 * 2);
    __hip_bfloat16* W3b = (__hip_bfloat16*)alloc(2 * 98304 * 2);
    __hip_bfloat16* ea1 = (__hip_bfloat16*)alloc(CE * 128 * 2);
    __hip_bfloat16* ea2 = (__hip_bfloat16*)alloc(CE * 256 * 2);
    __hip_bfloat16* ea3 = (__hip_bfloat16*)alloc(CE * 384 * 2);
    int* cnt      = (int*)alloc(2048 * 4);
    int* rowstart = (int*)alloc(2049 * 4);
    int* cursor   = (int*)alloc(2048 * 4);
    int* elist    = (int*)alloc(CE * 4);

    // one-time bf16 casts (weights for both layers + edge_attr)
    k_f2b<<<(NEDGES * 32 + 255) / 256, 256, 0, stream>>>(edge_attr, eaB, NEDGES * 32);
    k_f2b<<<(2 * 4096 + 255) / 256, 256, 0, stream>>>(Ws1, W1b, 2 * 4096);
    k_f2b<<<(2 * 32768 + 255) / 256, 256, 0, stream>>>(Ws2, W2b, 2 * 32768);
    k_f2b<<<(2 * 98304 + 255) / 256, 256, 0, stream>>>(Ws3, W3b, 2 * 98304);

    const float* Xin = X;
    for (int l = 0; l < 2; l++) {
        const float* b1 = bs1 + (size_t)l * H;
        const float* b2 = bs2 + (size_t)l * 2 * H;
        const float* b3 = bs3 + (size_t)l * 3 * H;
        const __hip_bfloat16* W1 = W1b + (size_t)l * 4096;
        const __hip_bfloat16* W2 = W2b + (size_t)l * 32768;
        const __hip_bfloat16* W3 = W3b + (size_t)l * 98304;
        const float* Wtl = Wt + (size_t)l * 6 * H * H;

        k_node_prep<<<NH / 256, 256, 0, stream>>>(Xin, Xn, D);
        k_gemm_mix<<<dim3(NATOMS / BM, H / BN, 9), 256, 0, stream>>>(D, Wtl, Ydec);
        hipMemsetAsync(Mdec, 0, nodeBytes, stream);

        for (size_t e0 = 0; e0 < NEDGES; e0 += CE) {
            // edge MLP (bf16 MFMA)
            k_mlp<32, 128, 1><<<dim3(CE / 128, 128 / 64), 256, 0, stream>>>(
                eaB + e0 * 32, W1, b1, nullptr, ea1);
            k_mlp<128, 256, 1><<<dim3(CE / 128, 256 / 64), 256, 0, stream>>>(
                ea1, W2, b2, nullptr, ea2);
            k_mlp<256, 384, 2><<<dim3(CE / 128, 384 / 64), 256, 0, stream>>>(
                ea2, W3, b3, edge_weight + e0, ea3);
            // CSR build for this chunk, then gather-accumulate
            hipMemsetAsync(cnt, 0, 2048 * sizeof(int), stream);
            k_hist<<<(CE + 255) / 256, 256, 0, stream>>>(eidx, (int)e0, (int)CE, cnt);
            k_scan<<<1, 256, 0, stream>>>(cnt, rowstart, cursor);
            k_fill<<<(CE + 255) / 256, 256, 0, stream>>>(eidx, (int)e0, (int)CE, cursor, elist);
            k_gather<<<NH / 256, 256, 0, stream>>>(
                ea3, eidx, rowstart, elist, Ydec, Mdec, (int)e0);
        }

        k_abnorm<<<NH / 256, 256, 0, stream>>>(Mdec, Ydec, q, D /*Tdec*/);
        k_gemm_mix<<<dim3(NATOMS / BM, H / BN, 9), 256, 0, stream>>>(
            D, Wtl + 3 * H * H, Ydec /*dXdec*/);
        k_final<<<NH / 256, 256, 0, stream>>>(Ydec, Xn, q, Xout);

        Xin = Xout;
    }
}

// Round 4
// 237.334 us; speedup vs baseline: 2.6187x; 1.2201x over previous
//
#include <hip/hip_runtime.h>
#include <hip/hip_bf16.h>
#include <math.h>

#define H 128
#define R 32
#define NATOMS 2048
#define NEDGES 32768
#define NH (NATOMS * H)          // 262144 (n,h) pairs
#define CUTOFF_F 4.5f
#define PI_OVER_CUTOFF 0.6981317007977318f

typedef __bf16 bf16x8 __attribute__((ext_vector_type(8)));
typedef float f32x4 __attribute__((ext_vector_type(4)));
typedef short short8 __attribute__((ext_vector_type(8)));

// ---------------------------------------------------------------------------
__device__ __forceinline__ float silu_f(float x) {
    return x / (1.f + __expf(-x));
}
__device__ __forceinline__ float b2f(unsigned short u) {
    return __uint_as_float(((unsigned)u) << 16);
}
__device__ __forceinline__ unsigned short f2b(float f) {
    __hip_bfloat16 h = __float2bfloat16(f);
    return __builtin_bit_cast(unsigned short, h);
}

// Build full 3x3 from decomposition [i0, a01, a02, a12, s00, s01, s02, s11, s12]
__device__ __forceinline__ void build_full(const float d[9], float m[9]) {
    float i0 = d[0], a01 = d[1], a02 = d[2], a12 = d[3];
    float s00 = d[4], s01 = d[5], s02 = d[6], s11 = d[7], s12 = d[8];
    float s22 = -(s00 + s11);
    m[0] = i0 + s00;  m[1] = a01 + s01;  m[2] = a02 + s02;
    m[3] = s01 - a01; m[4] = i0 + s11;   m[5] = a12 + s12;
    m[6] = s02 - a02; m[7] = s12 - a12;  m[8] = i0 + s22;
}

// ---------------------------------------------------------------------------
__global__ __launch_bounds__(256) void k_f2b(
        const float* __restrict__ in, __hip_bfloat16* __restrict__ out, int n) {
    int i = blockIdx.x * 256 + threadIdx.x;
    if (i < n) out[i] = __float2bfloat16(in[i]);
}

// ---------------------------------------------------------------------------
// Node prep: X -> Xn (normalized fp32 [nh][9]) and bf16 decomposition planes Db
__global__ __launch_bounds__(256) void k_node_prep(
        const float* __restrict__ X, float* __restrict__ Xn,
        __hip_bfloat16* __restrict__ Db) {
    int i = blockIdx.x * 256 + threadIdx.x;
    if (i >= NH) return;
    const float* x = X + (size_t)i * 9;
    float v[9];
    float ss = 0.f;
#pragma unroll
    for (int j = 0; j < 9; j++) { v[j] = x[j]; ss += v[j] * v[j]; }
    float inv = 1.f / (ss + 1.f);
#pragma unroll
    for (int j = 0; j < 9; j++) { v[j] *= inv; Xn[(size_t)i * 9 + j] = v[j]; }
    float i0 = (v[0] + v[4] + v[8]) * (1.f / 3.f);
    unsigned short* D = (unsigned short*)Db;
    D[0 * NH + i] = f2b(i0);
    D[1 * NH + i] = f2b(0.5f * (v[1] - v[3]));
    D[2 * NH + i] = f2b(0.5f * (v[2] - v[6]));
    D[3 * NH + i] = f2b(0.5f * (v[5] - v[7]));
    D[4 * NH + i] = f2b(v[0] - i0);
    D[5 * NH + i] = f2b(0.5f * (v[1] + v[3]));
    D[6 * NH + i] = f2b(0.5f * (v[2] + v[6]));
    D[7 * NH + i] = f2b(v[4] - i0);
    D[8 * NH + i] = f2b(0.5f * (v[5] + v[7]));
}

// ---------------------------------------------------------------------------
// Shared bf16 MFMA 128x64 tile-GEMM core (double-buffered global_load_lds,
// XOR-swizzle: linear LDS dest + pre-swizzled global source + swizzled read).
template <int K>
struct TG {
    static constexpr int BKm = (K >= 64) ? 64 : 32;
    static constexpr int RB  = BKm * 2;
    static constexpr int SWZ = (BKm == 64) ? 7 : 3;
    static constexpr int NIT = K / BKm;
    static constexpr int ABYTES = 128 * RB;
    static constexpr int BBYTES = 64 * RB;
    static constexpr int AISS = ABYTES / 4096;
    static constexpr int BISS = BBYTES / 4096;
    static constexpr int LDSB = ABYTES + BBYTES;
};

template <int K>
__device__ __forceinline__ void tile_gemm_run(
        const __hip_bfloat16* __restrict__ A, const __hip_bfloat16* __restrict__ W,
        int m0, int n0, char* lds, f32x4 acc[4][2]) {
    using T = TG<K>;
    const int t = threadIdx.x;
    const int lane = t & 63;
    const int w = t >> 6;
    const int wm = (w & 1) * 64;
    const int wn = (w >> 1) * 32;

    auto stage = [&](int b, int it) {
        const int k0 = it * T::BKm;
        char* As = lds + b * T::LDSB;
        char* Bs = As + T::ABYTES;
#pragma unroll
        for (int i = 0; i < T::AISS; i++) {
            int base = (w * T::AISS + i) * 1024;
            int lin = base + lane * 16;
            int row = lin / T::RB;
            int slot = (lin % T::RB) >> 4;
            int sl = slot ^ (row & T::SWZ);
            const char* src = (const char*)(A + (size_t)(m0 + row) * K + k0) + sl * 16;
            __builtin_amdgcn_global_load_lds(
                (const __attribute__((address_space(1))) void*)src,
                (__attribute__((address_space(3))) void*)(As + base), 16, 0, 0);
        }
#pragma unroll
        for (int i = 0; i < T::BISS; i++) {
            int base = (w * T::BISS + i) * 1024;
            int lin = base + lane * 16;
            int row = lin / T::RB;
            int slot = (lin % T::RB) >> 4;
            int sl = slot ^ (row & T::SWZ);
            const char* src = (const char*)(W + (size_t)(n0 + row) * K + k0) + sl * 16;
            __builtin_amdgcn_global_load_lds(
                (const __attribute__((address_space(1))) void*)src,
                (__attribute__((address_space(3))) void*)(Bs + base), 16, 0, 0);
        }
    };

    auto compute = [&](int b) {
        const char* As = lds + b * T::LDSB;
        const char* Bs = As + T::ABYTES;
        const int rA = wm + (lane & 15);
        const int rB = wn + (lane & 15);
        const int c = lane >> 4;
#pragma unroll
        for (int kk = 0; kk < T::BKm / 32; kk++) {
            bf16x8 av[4], bv[2];
#pragma unroll
            for (int mf = 0; mf < 4; mf++) {
                int row = rA + mf * 16;
                int sp = (kk * 4 + c) ^ (row & T::SWZ);
                av[mf] = __builtin_bit_cast(bf16x8,
                    *(const short8*)(As + row * T::RB + sp * 16));
            }
#pragma unroll
            for (int nf = 0; nf < 2; nf++) {
                int row = rB + nf * 16;
                int sp = (kk * 4 + c) ^ (row & T::SWZ);
                bv[nf] = __builtin_bit_cast(bf16x8,
                    *(const short8*)(Bs + row * T::RB + sp * 16));
            }
#pragma unroll
            for (int mf = 0; mf < 4; mf++)
#pragma unroll
                for (int nf = 0; nf < 2; nf++)
                    acc[mf][nf] = __builtin_amdgcn_mfma_f32_16x16x32_bf16(
                        av[mf], bv[nf], acc[mf][nf], 0, 0, 0);
        }
    };

    stage(0, 0);
    asm volatile("s_waitcnt vmcnt(0)" ::: "memory");
    __syncthreads();
    for (int it = 0; it < T::NIT; it++) {
        int b = it & 1;
        if (it + 1 < T::NIT) stage(b ^ 1, it + 1);
        compute(b);
        asm volatile("s_waitcnt vmcnt(0)" ::: "memory");
        __syncthreads();
    }
}

// ---------------------------------------------------------------------------
// Edge-MLP GEMM: Out[m,n] = epi( sum_k A[m,k]*W[n,k] ), bf16 out.
// MODE 1: +bias, silu; MODE 2: +bias, silu, *cutoff(ew[m]), permuted [E][3][H] out.
template <int K, int N, int MODE>
__global__ __launch_bounds__(256) void k_mlp(
        const __hip_bfloat16* __restrict__ A, const __hip_bfloat16* __restrict__ W,
        const float* __restrict__ bias, const float* __restrict__ ew,
        __hip_bfloat16* __restrict__ Out) {
    __shared__ char lds[2 * TG<K>::LDSB];
    const int lane = threadIdx.x & 63;
    const int w = threadIdx.x >> 6;
    const int wm = (w & 1) * 64, wn = (w >> 1) * 32;
    const int m0 = blockIdx.x * 128, n0 = blockIdx.y * 64;
    f32x4 acc[4][2] = {};
    tile_gemm_run<K>(A, W, m0, n0, lds, acc);

#pragma unroll
    for (int mf = 0; mf < 4; mf++) {
#pragma unroll
        for (int r = 0; r < 4; r++) {
            int row = m0 + wm + mf * 16 + (lane >> 4) * 4 + r;
            float cs = 1.f;
            if (MODE == 2) {
                float wv = ew[row];
                cs = (wv < CUTOFF_F) ? 0.5f * (__cosf(wv * PI_OVER_CUTOFF) + 1.f) : 0.f;
            }
#pragma unroll
            for (int nf = 0; nf < 2; nf++) {
                int col = n0 + wn + nf * 16 + (lane & 15);
                float x = acc[mf][nf][r];
                x += bias[col];
                x = silu_f(x);
                if (MODE == 2) {
                    x *= cs;
                    // permuted layout [E][3][H]: comp = col%3, h = col/3
                    Out[(size_t)row * 384 + (col % 3) * 128 + (col / 3)] =
                        __float2bfloat16(x);
                } else {
                    Out[(size_t)row * N + col] = __float2bfloat16(x);
                }
            }
        }
    }
}

// Channel-mix: 9 planes [2048,128] @ Wt-part [128,128] -> fp32 plane.
__global__ __launch_bounds__(256) void k_mix(
        const __hip_bfloat16* __restrict__ Db, const __hip_bfloat16* __restrict__ Wtb,
        float* __restrict__ Outp, int partOff) {
    __shared__ char lds[2 * TG<128>::LDSB];
    int c = blockIdx.z;
    int part = (c == 0) ? 0 : ((c < 4) ? 1 : 2);
    const __hip_bfloat16* A = Db + (size_t)c * NH;
    const __hip_bfloat16* W = Wtb + (size_t)(partOff + part) * H * H;
    float* Out = Outp + (size_t)c * NH;
    const int lane = threadIdx.x & 63;
    const int w = threadIdx.x >> 6;
    const int wm = (w & 1) * 64, wn = (w >> 1) * 32;
    const int m0 = blockIdx.x * 128, n0 = blockIdx.y * 64;
    f32x4 acc[4][2] = {};
    tile_gemm_run<128>(A, W, m0, n0, lds, acc);
#pragma unroll
    for (int mf = 0; mf < 4; mf++)
#pragma unroll
        for (int r = 0; r < 4; r++) {
            int row = m0 + wm + mf * 16 + (lane >> 4) * 4 + r;
#pragma unroll
            for (int nf = 0; nf < 2; nf++) {
                int col = n0 + wn + nf * 16 + (lane & 15);
                Out[(size_t)row * H + col] = acc[mf][nf][r];
            }
        }
}

// ---------------------------------------------------------------------------
// CSR build (once; edge_index is static across layers)
__global__ __launch_bounds__(256) void k_hist(
        const int* __restrict__ eidx, int* __restrict__ cnt) {
    int e = blockIdx.x * 256 + threadIdx.x;
    if (e < NEDGES) atomicAdd(&cnt[eidx[e]], 1);
}

__global__ __launch_bounds__(256) void k_scan(
        const int* __restrict__ cnt, int* __restrict__ rowstart,
        int* __restrict__ cursor) {
    __shared__ int partial[256];
    int t = threadIdx.x;
    int loc[8];
    int run = 0;
#pragma unroll
    for (int j = 0; j < 8; j++) {
        int v = cnt[t * 8 + j];
        loc[j] = run; run += v;
    }
    partial[t] = run;
    __syncthreads();
    if (t == 0) {
        int acc = 0;
        for (int i = 0; i < 256; i++) { int v = partial[i]; partial[i] = acc; acc += v; }
        rowstart[2048] = acc;
    }
    __syncthreads();
    int base = partial[t];
#pragma unroll
    for (int j = 0; j < 8; j++) {
        rowstart[t * 8 + j] = base + loc[j];
        cursor[t * 8 + j] = base + loc[j];
    }
}

__global__ __launch_bounds__(256) void k_fill(
        const int* __restrict__ eidx, int* __restrict__ cursor,
        int* __restrict__ elist) {
    int e = blockIdx.x * 256 + threadIdx.x;
    if (e >= NEDGES) return;
    int src = eidx[e];
    int pos = atomicAdd(&cursor[src], 1);
    elist[pos] = e;
}

// ---------------------------------------------------------------------------
// Gather + fused abnorm. One thread per (n, h-pair).
// acc = M(n,h0..h0+1) in registers; epilogue computes AB = M@Y+Y@M, scale,
// norm, decompose -> Tb (bf16 planes).
__global__ __launch_bounds__(256) void k_gather_ab(
        const __hip_bfloat16* __restrict__ ea /*[E][3][H]*/,
        const int* __restrict__ eidx,
        const int* __restrict__ rowstart, const int* __restrict__ elist,
        const float* __restrict__ Ydec, const float* __restrict__ q,
        __hip_bfloat16* __restrict__ Tb) {
    int gid = blockIdx.x * 256 + threadIdx.x;   // NH/2 threads
    int n = gid >> 6;
    int h0 = (gid & 63) << 1;
    int beg = rowstart[n], end = rowstart[n + 1];
    float acc[9][2];
#pragma unroll
    for (int c = 0; c < 9; c++) { acc[c][0] = 0.f; acc[c][1] = 0.f; }
    for (int idx = beg; idx < end; ++idx) {
        int e = elist[idx];
        int dst = eidx[NEDGES + e];
        const unsigned short* eap = (const unsigned short*)ea + (size_t)e * 384 + h0;
        ushort2 u0 = *(const ushort2*)(eap);
        ushort2 u1 = *(const ushort2*)(eap + 128);
        ushort2 u2 = *(const ushort2*)(eap + 256);
        float w0a = b2f(u0.x), w0b = b2f(u0.y);
        float w1a = b2f(u1.x), w1b = b2f(u1.y);
        float w2a = b2f(u2.x), w2b = b2f(u2.y);
        int db = dst * H + h0;
        float2 y;
        y = *(const float2*)&Ydec[0 * NH + db]; acc[0][0] += w0a * y.x; acc[0][1] += w0b * y.y;
        y = *(const float2*)&Ydec[1 * NH + db]; acc[1][0] += w1a * y.x; acc[1][1] += w1b * y.y;
        y = *(const float2*)&Ydec[2 * NH + db]; acc[2][0] += w1a * y.x; acc[2][1] += w1b * y.y;
        y = *(const float2*)&Ydec[3 * NH + db]; acc[3][0] += w1a * y.x; acc[3][1] += w1b * y.y;
#pragma unroll
        for (int c = 4; c < 9; c++) {
            y = *(const float2*)&Ydec[c * NH + db];
            acc[c][0] += w2a * y.x; acc[c][1] += w2b * y.y;
        }
    }
    // fused abnorm for the two h columns
    int ib = n * H + h0;
    float scale = 1.f + 0.1f * q[n];
    float yd2[9][2];
#pragma unroll
    for (int c = 0; c < 9; c++) {
        float2 y = *(const float2*)&Ydec[c * NH + ib];
        yd2[c][0] = y.x; yd2[c][1] = y.y;
    }
    unsigned short outw[9][2];
#pragma unroll
    for (int col = 0; col < 2; col++) {
        float md[9], yd[9];
#pragma unroll
        for (int c = 0; c < 9; c++) { md[c] = acc[c][col]; yd[c] = yd2[c][col]; }
        float m[9], yf[9];
        build_full(md, m);
        build_full(yd, yf);
        float ab[9];
#pragma unroll
        for (int ii = 0; ii < 3; ii++)
#pragma unroll
            for (int jj = 0; jj < 3; jj++) {
                float s = 0.f;
#pragma unroll
                for (int kk = 0; kk < 3; kk++)
                    s += m[ii * 3 + kk] * yf[kk * 3 + jj] + yf[ii * 3 + kk] * m[kk * 3 + jj];
                ab[ii * 3 + jj] = s;
            }
        float nrm = 0.f;
#pragma unroll
        for (int j = 0; j < 9; j++) { ab[j] *= scale; nrm += ab[j] * ab[j]; }
        float inv = 1.f / (nrm + 1.f);
        float tr3 = (ab[0] + ab[4] + ab[8]) * (1.f / 3.f);
        outw[0][col] = f2b(tr3 * inv);
        outw[1][col] = f2b(0.5f * (ab[1] - ab[3]) * inv);
        outw[2][col] = f2b(0.5f * (ab[2] - ab[6]) * inv);
        outw[3][col] = f2b(0.5f * (ab[5] - ab[7]) * inv);
        outw[4][col] = f2b((ab[0] - tr3) * inv);
        outw[5][col] = f2b(0.5f * (ab[1] + ab[3]) * inv);
        outw[6][col] = f2b(0.5f * (ab[2] + ab[6]) * inv);
        outw[7][col] = f2b((ab[4] - tr3) * inv);
        outw[8][col] = f2b(0.5f * (ab[5] + ab[7]) * inv);
    }
    unsigned short* T = (unsigned short*)Tb;
#pragma unroll
    for (int c = 0; c < 9; c++) {
        ushort2 o; o.x = outw[c][0]; o.y = outw[c][1];
        *(ushort2*)(T + (size_t)c * NH + ib) = o;
    }
}

// ---------------------------------------------------------------------------
// Final: Xout = Xn + dX + (1+0.1q)*dX@dX.  PREP: also normalize+decompose
// Xout into Xn (fp32) and Db (bf16 planes) for the next layer.
template <bool PREP>
__global__ __launch_bounds__(256) void k_final(
        const float* __restrict__ dXdec, const float* __restrict__ Xn,
        const float* __restrict__ q, float* __restrict__ Xout,
        float* __restrict__ XnW, __hip_bfloat16* __restrict__ Db) {
    int i = blockIdx.x * 256 + threadIdx.x;
    if (i >= NH) return;
    float dd[9];
#pragma unroll
    for (int c = 0; c < 9; c++) dd[c] = dXdec[c * NH + i];
    float dx[9];
    build_full(dd, dx);
    float scale = 1.f + 0.1f * q[i >> 7];
    float out[9];
#pragma unroll
    for (int ii = 0; ii < 3; ii++)
#pragma unroll
        for (int jj = 0; jj < 3; jj++) {
            float s = 0.f;
#pragma unroll
            for (int kk = 0; kk < 3; kk++)
                s += dx[ii * 3 + kk] * dx[kk * 3 + jj];
            out[ii * 3 + jj] = Xn[(size_t)i * 9 + ii * 3 + jj] + dx[ii * 3 + jj] + scale * s;
        }
#pragma unroll
    for (int j = 0; j < 9; j++) Xout[(size_t)i * 9 + j] = out[j];
    if (PREP) {
        float ss = 0.f;
#pragma unroll
        for (int j = 0; j < 9; j++) ss += out[j] * out[j];
        float inv = 1.f / (ss + 1.f);
        float v[9];
#pragma unroll
        for (int j = 0; j < 9; j++) { v[j] = out[j] * inv; XnW[(size_t)i * 9 + j] = v[j]; }
        float i0 = (v[0] + v[4] + v[8]) * (1.f / 3.f);
        unsigned short* D = (unsigned short*)Db;
        D[0 * NH + i] = f2b(i0);
        D[1 * NH + i] = f2b(0.5f * (v[1] - v[3]));
        D[2 * NH + i] = f2b(0.5f * (v[2] - v[6]));
        D[3 * NH + i] = f2b(0.5f * (v[5] - v[7]));
        D[4 * NH + i] = f2b(v[0] - i0);
        D[5 * NH + i] = f2b(0.5f * (v[1] + v[3]));
        D[6 * NH + i] = f2b(0.5f * (v[2] + v[6]));
        D[7 * NH + i] = f2b(v[4] - i0);
        D[8 * NH + i] = f2b(0.5f * (v[5] + v[7]));
    }
}

// ---------------------------------------------------------------------------
extern "C" void kernel_launch(void* const* d_in, const int* in_sizes, int n_in,
                              void* d_out, int out_size, void* d_ws, size_t ws_size,
                              hipStream_t stream) {
    const float* X          = (const float*)d_in[0];
    const float* edge_attr  = (const float*)d_in[1];
    const float* edge_weight= (const float*)d_in[2];
    const float* q          = (const float*)d_in[3];
    const float* Ws1        = (const float*)d_in[4];
    const float* bs1        = (const float*)d_in[5];
    const float* Ws2        = (const float*)d_in[6];
    const float* bs2        = (const float*)d_in[7];
    const float* Ws3        = (const float*)d_in[8];
    const float* bs3        = (const float*)d_in[9];
    const float* Wt         = (const float*)d_in[10];
    const int*   eidx       = (const int*)d_in[11];
    float* Xout = (float*)d_out;

    char* p = (char*)d_ws;
    auto alloc = [&](size_t bytes) -> char* {
        char* r = p; p += (bytes + 255) & ~(size_t)255; return r;
    };
    size_t nodeBytes = (size_t)NH * 9 * sizeof(float);
    float* Xn   = (float*)alloc(nodeBytes);
    __hip_bfloat16* Db = (__hip_bfloat16*)alloc((size_t)NH * 9 * 2);  // D / T planes
    float* Ydec = (float*)alloc(nodeBytes);                            // Y, then dX
    __hip_bfloat16* eaB = (__hip_bfloat16*)alloc((size_t)NEDGES * 32 * 2);
    __hip_bfloat16* W1b = (__hip_bfloat16*)alloc(2 * 4096 * 2);
    __hip_bfloat16* W2b = (__hip_bfloat16*)alloc(2 * 32768 * 2);
    __hip_bfloat16* W3b = (__hip_bfloat16*)alloc(2 * 98304 * 2);
    __hip_bfloat16* Wtb = (__hip_bfloat16*)alloc(2 * 6 * 16384 * 2);
    __hip_bfloat16* ea1 = (__hip_bfloat16*)alloc((size_t)NEDGES * 128 * 2);
    __hip_bfloat16* ea2 = (__hip_bfloat16*)alloc((size_t)NEDGES * 256 * 2);
    __hip_bfloat16* ea3 = (__hip_bfloat16*)alloc((size_t)NEDGES * 384 * 2);
    int* cnt      = (int*)alloc(2048 * 4);
    int* rowstart = (int*)alloc(2049 * 4);
    int* cursor   = (int*)alloc(2048 * 4);
    int* elist    = (int*)alloc(NEDGES * 4);

    // one-time bf16 casts
    k_f2b<<<(NEDGES * 32 + 255) / 256, 256, 0, stream>>>(edge_attr, eaB, NEDGES * 32);
    k_f2b<<<(2 * 4096 + 255) / 256, 256, 0, stream>>>(Ws1, W1b, 2 * 4096);
    k_f2b<<<(2 * 32768 + 255) / 256, 256, 0, stream>>>(Ws2, W2b, 2 * 32768);
    k_f2b<<<(2 * 98304 + 255) / 256, 256, 0, stream>>>(Ws3, W3b, 2 * 98304);
    k_f2b<<<(2 * 6 * 16384 + 255) / 256, 256, 0, stream>>>(Wt, Wtb, 2 * 6 * 16384);

    // CSR once (edge_index static across layers)
    hipMemsetAsync(cnt, 0, 2048 * sizeof(int), stream);
    k_hist<<<NEDGES / 256, 256, 0, stream>>>(eidx, cnt);
    k_scan<<<1, 256, 0, stream>>>(cnt, rowstart, cursor);
    k_fill<<<NEDGES / 256, 256, 0, stream>>>(eidx, cursor, elist);

    k_node_prep<<<NH / 256, 256, 0, stream>>>(X, Xn, Db);

    for (int l = 0; l < 2; l++) {
        const float* b1 = bs1 + (size_t)l * H;
        const float* b2 = bs2 + (size_t)l * 2 * H;
        const float* b3 = bs3 + (size_t)l * 3 * H;
        const __hip_bfloat16* W1 = W1b + (size_t)l * 4096;
        const __hip_bfloat16* W2 = W2b + (size_t)l * 32768;
        const __hip_bfloat16* W3 = W3b + (size_t)l * 98304;
        const __hip_bfloat16* Wtl = Wtb + (size_t)l * 6 * 16384;

        // Y = chan_mix(decomposed Xn)
        k_mix<<<dim3(NATOMS / 128, 2, 9), 256, 0, stream>>>(Db, Wtl, Ydec, 0);
        // edge MLP
        k_mlp<32, 128, 1><<<dim3(NEDGES / 128, 2), 256, 0, stream>>>(
            eaB, W1, b1, nullptr, ea1);
        k_mlp<128, 256, 1><<<dim3(NEDGES / 128, 4), 256, 0, stream>>>(
            ea1, W2, b2, nullptr, ea2);
        k_mlp<256, 384, 2><<<dim3(NEDGES / 128, 6), 256, 0, stream>>>(
            ea2, W3, b3, edge_weight, ea3);
        // gather + fused abnorm -> Tb (reuses Db)
        k_gather_ab<<<NH / 512, 256, 0, stream>>>(
            ea3, eidx, rowstart, elist, Ydec, q, Db);
        // dX = chan_mix(T) (reuses Ydec)
        k_mix<<<dim3(NATOMS / 128, 2, 9), 256, 0, stream>>>(Db, Wtl, Ydec, 3);
        // final (+ fused node-prep for next layer)
        if (l == 0)
            k_final<true><<<NH / 256, 256, 0, stream>>>(Ydec, Xn, q, Xout, Xn, Db);
        else
            k_final<false><<<NH / 256, 256, 0, stream>>>(Ydec, Xn, q, Xout, nullptr, nullptr);
    }
}

// Round 5
// 231.673 us; speedup vs baseline: 2.6827x; 1.0244x over previous
//
#include <hip/hip_runtime.h>
#include <hip/hip_bf16.h>
#include <math.h>

#define H 128
#define R 32
#define NATOMS 2048
#define NEDGES 32768
#define NH (NATOMS * H)          // 262144 (n,h) pairs
#define CUTOFF_F 4.5f
#define PI_OVER_CUTOFF 0.6981317007977318f

typedef __bf16 bf16x8 __attribute__((ext_vector_type(8)));
typedef float f32x4 __attribute__((ext_vector_type(4)));
typedef short short8 __attribute__((ext_vector_type(8)));

// ---------------------------------------------------------------------------
__device__ __forceinline__ float silu_f(float x) {
    return x / (1.f + __expf(-x));
}
__device__ __forceinline__ float b2f(unsigned short u) {
    return __uint_as_float(((unsigned)u) << 16);
}
__device__ __forceinline__ unsigned short f2b(float f) {
    __hip_bfloat16 h = __float2bfloat16(f);
    return __builtin_bit_cast(unsigned short, h);
}

// Build full 3x3 from decomposition [i0, a01, a02, a12, s00, s01, s02, s11, s12]
__device__ __forceinline__ void build_full(const float d[9], float m[9]) {
    float i0 = d[0], a01 = d[1], a02 = d[2], a12 = d[3];
    float s00 = d[4], s01 = d[5], s02 = d[6], s11 = d[7], s12 = d[8];
    float s22 = -(s00 + s11);
    m[0] = i0 + s00;  m[1] = a01 + s01;  m[2] = a02 + s02;
    m[3] = s01 - a01; m[4] = i0 + s11;   m[5] = a12 + s12;
    m[6] = s02 - a02; m[7] = s12 - a12;  m[8] = i0 + s22;
}

// ---------------------------------------------------------------------------
__global__ __launch_bounds__(256) void k_f2b(
        const float* __restrict__ in, __hip_bfloat16* __restrict__ out, int n) {
    int i = blockIdx.x * 256 + threadIdx.x;
    if (i < n) out[i] = __float2bfloat16(in[i]);
}

// ---------------------------------------------------------------------------
// Node prep: X -> Xn (normalized fp32 [nh][9]) and bf16 decomposition planes Db
__global__ __launch_bounds__(256) void k_node_prep(
        const float* __restrict__ X, float* __restrict__ Xn,
        __hip_bfloat16* __restrict__ Db) {
    int i = blockIdx.x * 256 + threadIdx.x;
    if (i >= NH) return;
    const float* x = X + (size_t)i * 9;
    float v[9];
    float ss = 0.f;
#pragma unroll
    for (int j = 0; j < 9; j++) { v[j] = x[j]; ss += v[j] * v[j]; }
    float inv = 1.f / (ss + 1.f);
#pragma unroll
    for (int j = 0; j < 9; j++) { v[j] *= inv; Xn[(size_t)i * 9 + j] = v[j]; }
    float i0 = (v[0] + v[4] + v[8]) * (1.f / 3.f);
    unsigned short* D = (unsigned short*)Db;
    D[0 * NH + i] = f2b(i0);
    D[1 * NH + i] = f2b(0.5f * (v[1] - v[3]));
    D[2 * NH + i] = f2b(0.5f * (v[2] - v[6]));
    D[3 * NH + i] = f2b(0.5f * (v[5] - v[7]));
    D[4 * NH + i] = f2b(v[0] - i0);
    D[5 * NH + i] = f2b(0.5f * (v[1] + v[3]));
    D[6 * NH + i] = f2b(0.5f * (v[2] + v[6]));
    D[7 * NH + i] = f2b(v[4] - i0);
    D[8 * NH + i] = f2b(0.5f * (v[5] + v[7]));
}

// ---------------------------------------------------------------------------
// Shared bf16 MFMA 128x64 tile-GEMM core (double-buffered global_load_lds,
// XOR-swizzle: linear LDS dest + pre-swizzled global source + swizzled read).
template <int K>
struct TG {
    static constexpr int BKm = (K >= 64) ? 64 : 32;
    static constexpr int RB  = BKm * 2;
    static constexpr int SWZ = (BKm == 64) ? 7 : 3;
    static constexpr int NIT = K / BKm;
    static constexpr int ABYTES = 128 * RB;
    static constexpr int BBYTES = 64 * RB;
    static constexpr int AISS = ABYTES / 4096;
    static constexpr int BISS = BBYTES / 4096;
    static constexpr int LDSB = ABYTES + BBYTES;
};

template <int K>
__device__ __forceinline__ void tile_gemm_run(
        const __hip_bfloat16* __restrict__ A, const __hip_bfloat16* __restrict__ W,
        int m0, int n0, char* lds, f32x4 acc[4][2]) {
    using T = TG<K>;
    const int t = threadIdx.x;
    const int lane = t & 63;
    const int w = t >> 6;

    auto stage = [&](int b, int it) {
        const int k0 = it * T::BKm;
        char* As = lds + b * T::LDSB;
        char* Bs = As + T::ABYTES;
#pragma unroll
        for (int i = 0; i < T::AISS; i++) {
            int base = (w * T::AISS + i) * 1024;
            int lin = base + lane * 16;
            int row = lin / T::RB;
            int slot = (lin % T::RB) >> 4;
            int sl = slot ^ (row & T::SWZ);
            const char* src = (const char*)(A + (size_t)(m0 + row) * K + k0) + sl * 16;
            __builtin_amdgcn_global_load_lds(
                (const __attribute__((address_space(1))) void*)src,
                (__attribute__((address_space(3))) void*)(As + base), 16, 0, 0);
        }
#pragma unroll
        for (int i = 0; i < T::BISS; i++) {
            int base = (w * T::BISS + i) * 1024;
            int lin = base + lane * 16;
            int row = lin / T::RB;
            int slot = (lin % T::RB) >> 4;
            int sl = slot ^ (row & T::SWZ);
            const char* src = (const char*)(W + (size_t)(n0 + row) * K + k0) + sl * 16;
            __builtin_amdgcn_global_load_lds(
                (const __attribute__((address_space(1))) void*)src,
                (__attribute__((address_space(3))) void*)(Bs + base), 16, 0, 0);
        }
    };

    auto compute = [&](int b) {
        const char* As = lds + b * T::LDSB;
        const char* Bs = As + T::ABYTES;
        const int wm = (w & 1) * 64;
        const int wn = (w >> 1) * 32;
        const int rA = wm + (lane & 15);
        const int rB = wn + (lane & 15);
        const int c = lane >> 4;
#pragma unroll
        for (int kk = 0; kk < T::BKm / 32; kk++) {
            bf16x8 av[4], bv[2];
#pragma unroll
            for (int mf = 0; mf < 4; mf++) {
                int row = rA + mf * 16;
                int sp = (kk * 4 + c) ^ (row & T::SWZ);
                av[mf] = __builtin_bit_cast(bf16x8,
                    *(const short8*)(As + row * T::RB + sp * 16));
            }
#pragma unroll
            for (int nf = 0; nf < 2; nf++) {
                int row = rB + nf * 16;
                int sp = (kk * 4 + c) ^ (row & T::SWZ);
                bv[nf] = __builtin_bit_cast(bf16x8,
                    *(const short8*)(Bs + row * T::RB + sp * 16));
            }
#pragma unroll
            for (int mf = 0; mf < 4; mf++)
#pragma unroll
                for (int nf = 0; nf < 2; nf++)
                    acc[mf][nf] = __builtin_amdgcn_mfma_f32_16x16x32_bf16(
                        av[mf], bv[nf], acc[mf][nf], 0, 0, 0);
        }
    };

    stage(0, 0);
    asm volatile("s_waitcnt vmcnt(0)" ::: "memory");
    __syncthreads();
    for (int it = 0; it < T::NIT; it++) {
        int b = it & 1;
        if (it + 1 < T::NIT) stage(b ^ 1, it + 1);
        compute(b);
        asm volatile("s_waitcnt vmcnt(0)" ::: "memory");
        __syncthreads();
    }
}

// ---------------------------------------------------------------------------
// Edge-MLP GEMM: Out[m,n] = epi( sum_k A[m,k]*W[n,k] ), bf16 out.
// MODE 1: +bias, silu; MODE 2: +bias, silu, *cutoff(ew[m]), permuted [E][3][H] out.
template <int K, int N, int MODE>
__global__ __launch_bounds__(256) void k_mlp(
        const __hip_bfloat16* __restrict__ A, const __hip_bfloat16* __restrict__ W,
        const float* __restrict__ bias, const float* __restrict__ ew,
        __hip_bfloat16* __restrict__ Out) {
    __shared__ char lds[2 * TG<K>::LDSB];
    const int lane = threadIdx.x & 63;
    const int w = threadIdx.x >> 6;
    const int wm = (w & 1) * 64, wn = (w >> 1) * 32;
    const int m0 = blockIdx.x * 128, n0 = blockIdx.y * 64;
    f32x4 acc[4][2] = {};
    tile_gemm_run<K>(A, W, m0, n0, lds, acc);

#pragma unroll
    for (int mf = 0; mf < 4; mf++) {
#pragma unroll
        for (int r = 0; r < 4; r++) {
            int row = m0 + wm + mf * 16 + (lane >> 4) * 4 + r;
            float cs = 1.f;
            if (MODE == 2) {
                float wv = ew[row];
                cs = (wv < CUTOFF_F) ? 0.5f * (__cosf(wv * PI_OVER_CUTOFF) + 1.f) : 0.f;
            }
#pragma unroll
            for (int nf = 0; nf < 2; nf++) {
                int col = n0 + wn + nf * 16 + (lane & 15);
                float x = acc[mf][nf][r];
                x += bias[col];
                x = silu_f(x);
                if (MODE == 2) {
                    x *= cs;
                    // permuted layout [E][3][H]: comp = col%3, h = col/3
                    Out[(size_t)row * 384 + (col % 3) * 128 + (col / 3)] =
                        __float2bfloat16(x);
                } else {
                    Out[(size_t)row * N + col] = __float2bfloat16(x);
                }
            }
        }
    }
}

// Channel-mix: 9 planes [2048,128] @ Wt-part [128,128] -> bf16 plane.
__global__ __launch_bounds__(256) void k_mix(
        const __hip_bfloat16* __restrict__ Db, const __hip_bfloat16* __restrict__ Wtb,
        __hip_bfloat16* __restrict__ Outp, int partOff) {
    __shared__ char lds[2 * TG<128>::LDSB];
    int c = blockIdx.z;
    int part = (c == 0) ? 0 : ((c < 4) ? 1 : 2);
    const __hip_bfloat16* A = Db + (size_t)c * NH;
    const __hip_bfloat16* W = Wtb + (size_t)(partOff + part) * H * H;
    __hip_bfloat16* Out = Outp + (size_t)c * NH;
    const int lane = threadIdx.x & 63;
    const int w = threadIdx.x >> 6;
    const int wm = (w & 1) * 64, wn = (w >> 1) * 32;
    const int m0 = blockIdx.x * 128, n0 = blockIdx.y * 64;
    f32x4 acc[4][2] = {};
    tile_gemm_run<128>(A, W, m0, n0, lds, acc);
#pragma unroll
    for (int mf = 0; mf < 4; mf++)
#pragma unroll
        for (int r = 0; r < 4; r++) {
            int row = m0 + wm + mf * 16 + (lane >> 4) * 4 + r;
#pragma unroll
            for (int nf = 0; nf < 2; nf++) {
                int col = n0 + wn + nf * 16 + (lane & 15);
                Out[(size_t)row * H + col] = __float2bfloat16(acc[mf][nf][r]);
            }
        }
}

// ---------------------------------------------------------------------------
// CSR build (once; edge_index is static across layers)
__global__ __launch_bounds__(256) void k_hist(
        const int* __restrict__ eidx, int* __restrict__ cnt) {
    int e = blockIdx.x * 256 + threadIdx.x;
    if (e < NEDGES) atomicAdd(&cnt[eidx[e]], 1);
}

__global__ __launch_bounds__(256) void k_scan(
        const int* __restrict__ cnt, int* __restrict__ rowstart,
        int* __restrict__ cursor) {
    __shared__ int partial[256];
    int t = threadIdx.x;
    int loc[8];
    int run = 0;
#pragma unroll
    for (int j = 0; j < 8; j++) {
        int v = cnt[t * 8 + j];
        loc[j] = run; run += v;
    }
    partial[t] = run;
    __syncthreads();
    if (t == 0) {
        int acc = 0;
        for (int i = 0; i < 256; i++) { int v = partial[i]; partial[i] = acc; acc += v; }
        rowstart[2048] = acc;
    }
    __syncthreads();
    int base = partial[t];
#pragma unroll
    for (int j = 0; j < 8; j++) {
        rowstart[t * 8 + j] = base + loc[j];
        cursor[t * 8 + j] = base + loc[j];
    }
}

__global__ __launch_bounds__(256) void k_fill(
        const int* __restrict__ eidx, int* __restrict__ cursor,
        int* __restrict__ elist) {
    int e = blockIdx.x * 256 + threadIdx.x;
    if (e >= NEDGES) return;
    int src = eidx[e];
    int pos = atomicAdd(&cursor[src], 1);
    elist[pos] = e;
}

// ---------------------------------------------------------------------------
// Gather + fused abnorm. One wave per node, one thread per h-pair.
// Y planes are bf16. acc = M(n,h0..h0+1) in registers; epilogue computes
// AB = M@Y+Y@M, scale, norm, decompose -> Tb (bf16 planes).
__global__ __launch_bounds__(256) void k_gather_ab(
        const __hip_bfloat16* __restrict__ ea /*[E][3][H]*/,
        const int* __restrict__ eidx,
        const int* __restrict__ rowstart, const int* __restrict__ elist,
        const __hip_bfloat16* __restrict__ Yb, const float* __restrict__ q,
        __hip_bfloat16* __restrict__ Tb) {
    int gid = blockIdx.x * 256 + threadIdx.x;   // NH/2 threads
    int n = gid >> 6;
    int h0 = (gid & 63) << 1;
    int beg = rowstart[n], end = rowstart[n + 1];
    const unsigned short* Y = (const unsigned short*)Yb;
    float acc[9][2];
#pragma unroll
    for (int c = 0; c < 9; c++) { acc[c][0] = 0.f; acc[c][1] = 0.f; }
    for (int idx = beg; idx < end; ++idx) {
        int e = elist[idx];
        int dst = eidx[NEDGES + e];
        const unsigned short* eap = (const unsigned short*)ea + (size_t)e * 384 + h0;
        ushort2 u0 = *(const ushort2*)(eap);
        ushort2 u1 = *(const ushort2*)(eap + 128);
        ushort2 u2 = *(const ushort2*)(eap + 256);
        float w0a = b2f(u0.x), w0b = b2f(u0.y);
        float w1a = b2f(u1.x), w1b = b2f(u1.y);
        float w2a = b2f(u2.x), w2b = b2f(u2.y);
        int db = dst * H + h0;
        ushort2 y;
        y = *(const ushort2*)(Y + 0 * NH + db); acc[0][0] += w0a * b2f(y.x); acc[0][1] += w0b * b2f(y.y);
        y = *(const ushort2*)(Y + 1 * NH + db); acc[1][0] += w1a * b2f(y.x); acc[1][1] += w1b * b2f(y.y);
        y = *(const ushort2*)(Y + 2 * NH + db); acc[2][0] += w1a * b2f(y.x); acc[2][1] += w1b * b2f(y.y);
        y = *(const ushort2*)(Y + 3 * NH + db); acc[3][0] += w1a * b2f(y.x); acc[3][1] += w1b * b2f(y.y);
#pragma unroll
        for (int c = 4; c < 9; c++) {
            y = *(const ushort2*)(Y + c * NH + db);
            acc[c][0] += w2a * b2f(y.x); acc[c][1] += w2b * b2f(y.y);
        }
    }
    // fused abnorm for the two h columns
    int ib = n * H + h0;
    float scale = 1.f + 0.1f * q[n];
    float yd2[9][2];
#pragma unroll
    for (int c = 0; c < 9; c++) {
        ushort2 y = *(const ushort2*)(Y + (size_t)c * NH + ib);
        yd2[c][0] = b2f(y.x); yd2[c][1] = b2f(y.y);
    }
    unsigned short outw[9][2];
#pragma unroll
    for (int col = 0; col < 2; col++) {
        float md[9], yd[9];
#pragma unroll
        for (int c = 0; c < 9; c++) { md[c] = acc[c][col]; yd[c] = yd2[c][col]; }
        float m[9], yf[9];
        build_full(md, m);
        build_full(yd, yf);
        float ab[9];
#pragma unroll
        for (int ii = 0; ii < 3; ii++)
#pragma unroll
            for (int jj = 0; jj < 3; jj++) {
                float s = 0.f;
#pragma unroll
                for (int kk = 0; kk < 3; kk++)
                    s += m[ii * 3 + kk] * yf[kk * 3 + jj] + yf[ii * 3 + kk] * m[kk * 3 + jj];
                ab[ii * 3 + jj] = s;
            }
        float nrm = 0.f;
#pragma unroll
        for (int j = 0; j < 9; j++) { ab[j] *= scale; nrm += ab[j] * ab[j]; }
        float inv = 1.f / (nrm + 1.f);
        float tr3 = (ab[0] + ab[4] + ab[8]) * (1.f / 3.f);
        outw[0][col] = f2b(tr3 * inv);
        outw[1][col] = f2b(0.5f * (ab[1] - ab[3]) * inv);
        outw[2][col] = f2b(0.5f * (ab[2] - ab[6]) * inv);
        outw[3][col] = f2b(0.5f * (ab[5] - ab[7]) * inv);
        outw[4][col] = f2b((ab[0] - tr3) * inv);
        outw[5][col] = f2b(0.5f * (ab[1] + ab[3]) * inv);
        outw[6][col] = f2b(0.5f * (ab[2] + ab[6]) * inv);
        outw[7][col] = f2b((ab[4] - tr3) * inv);
        outw[8][col] = f2b(0.5f * (ab[5] + ab[7]) * inv);
    }
    unsigned short* T = (unsigned short*)Tb;
#pragma unroll
    for (int c = 0; c < 9; c++) {
        ushort2 o; o.x = outw[c][0]; o.y = outw[c][1];
        *(ushort2*)(T + (size_t)c * NH + ib) = o;
    }
}

// ---------------------------------------------------------------------------
// Final: Xout = Xn + dX + (1+0.1q)*dX@dX.  dX planes are bf16.
// PREP: also normalize+decompose Xout into Xn (fp32) and Db (bf16) for next layer.
template <bool PREP>
__global__ __launch_bounds__(256) void k_final(
        const __hip_bfloat16* __restrict__ dXb, const float* __restrict__ Xn,
        const float* __restrict__ q, float* __restrict__ Xout,
        float* __restrict__ XnW, __hip_bfloat16* __restrict__ Db) {
    int i = blockIdx.x * 256 + threadIdx.x;
    if (i >= NH) return;
    const unsigned short* dX = (const unsigned short*)dXb;
    float dd[9];
#pragma unroll
    for (int c = 0; c < 9; c++) dd[c] = b2f(dX[(size_t)c * NH + i]);
    float dx[9];
    build_full(dd, dx);
    float scale = 1.f + 0.1f * q[i >> 7];
    float out[9];
#pragma unroll
    for (int ii = 0; ii < 3; ii++)
#pragma unroll
        for (int jj = 0; jj < 3; jj++) {
            float s = 0.f;
#pragma unroll
            for (int kk = 0; kk < 3; kk++)
                s += dx[ii * 3 + kk] * dx[kk * 3 + jj];
            out[ii * 3 + jj] = Xn[(size_t)i * 9 + ii * 3 + jj] + dx[ii * 3 + jj] + scale * s;
        }
#pragma unroll
    for (int j = 0; j < 9; j++) Xout[(size_t)i * 9 + j] = out[j];
    if (PREP) {
        float ss = 0.f;
#pragma unroll
        for (int j = 0; j < 9; j++) ss += out[j] * out[j];
        float inv = 1.f / (ss + 1.f);
        float v[9];
#pragma unroll
        for (int j = 0; j < 9; j++) { v[j] = out[j] * inv; XnW[(size_t)i * 9 + j] = v[j]; }
        float i0 = (v[0] + v[4] + v[8]) * (1.f / 3.f);
        unsigned short* D = (unsigned short*)Db;
        D[0 * NH + i] = f2b(i0);
        D[1 * NH + i] = f2b(0.5f * (v[1] - v[3]));
        D[2 * NH + i] = f2b(0.5f * (v[2] - v[6]));
        D[3 * NH + i] = f2b(0.5f * (v[5] - v[7]));
        D[4 * NH + i] = f2b(v[0] - i0);
        D[5 * NH + i] = f2b(0.5f * (v[1] + v[3]));
        D[6 * NH + i] = f2b(0.5f * (v[2] + v[6]));
        D[7 * NH + i] = f2b(v[4] - i0);
        D[8 * NH + i] = f2b(0.5f * (v[5] + v[7]));
    }
}

// ---------------------------------------------------------------------------
extern "C" void kernel_launch(void* const* d_in, const int* in_sizes, int n_in,
                              void* d_out, int out_size, void* d_ws, size_t ws_size,
                              hipStream_t stream) {
    const float* X          = (const float*)d_in[0];
    const float* edge_attr  = (const float*)d_in[1];
    const float* edge_weight= (const float*)d_in[2];
    const float* q          = (const float*)d_in[3];
    const float* Ws1        = (const float*)d_in[4];
    const float* bs1        = (const float*)d_in[5];
    const float* Ws2        = (const float*)d_in[6];
    const float* bs2        = (const float*)d_in[7];
    const float* Ws3        = (const float*)d_in[8];
    const float* bs3        = (const float*)d_in[9];
    const float* Wt         = (const float*)d_in[10];
    const int*   eidx       = (const int*)d_in[11];
    float* Xout = (float*)d_out;

    char* p = (char*)d_ws;
    auto alloc = [&](size_t bytes) -> char* {
        char* r = p; p += (bytes + 255) & ~(size_t)255; return r;
    };
    size_t nodeBytes = (size_t)NH * 9 * sizeof(float);
    float* Xn   = (float*)alloc(nodeBytes);
    __hip_bfloat16* Db = (__hip_bfloat16*)alloc((size_t)NH * 9 * 2);  // D / T planes
    __hip_bfloat16* Yb = (__hip_bfloat16*)alloc((size_t)NH * 9 * 2);  // Y, then dX
    __hip_bfloat16* eaB = (__hip_bfloat16*)alloc((size_t)NEDGES * 32 * 2);
    __hip_bfloat16* W1b = (__hip_bfloat16*)alloc(2 * 4096 * 2);
    __hip_bfloat16* W2b = (__hip_bfloat16*)alloc(2 * 32768 * 2);
    __hip_bfloat16* W3b = (__hip_bfloat16*)alloc(2 * 98304 * 2);
    __hip_bfloat16* Wtb = (__hip_bfloat16*)alloc(2 * 6 * 16384 * 2);
    __hip_bfloat16* ea1 = (__hip_bfloat16*)alloc((size_t)NEDGES * 128 * 2);
    __hip_bfloat16* ea2 = (__hip_bfloat16*)alloc((size_t)NEDGES * 256 * 2);
    __hip_bfloat16* ea3 = (__hip_bfloat16*)alloc((size_t)NEDGES * 384 * 2);
    int* cnt      = (int*)alloc(2048 * 4);
    int* rowstart = (int*)alloc(2049 * 4);
    int* cursor   = (int*)alloc(2048 * 4);
    int* elist    = (int*)alloc(NEDGES * 4);

    // one-time bf16 casts
    k_f2b<<<(NEDGES * 32 + 255) / 256, 256, 0, stream>>>(edge_attr, eaB, NEDGES * 32);
    k_f2b<<<(2 * 4096 + 255) / 256, 256, 0, stream>>>(Ws1, W1b, 2 * 4096);
    k_f2b<<<(2 * 32768 + 255) / 256, 256, 0, stream>>>(Ws2, W2b, 2 * 32768);
    k_f2b<<<(2 * 98304 + 255) / 256, 256, 0, stream>>>(Ws3, W3b, 2 * 98304);
    k_f2b<<<(2 * 6 * 16384 + 255) / 256, 256, 0, stream>>>(Wt, Wtb, 2 * 6 * 16384);

    // CSR once (edge_index static across layers)
    hipMemsetAsync(cnt, 0, 2048 * sizeof(int), stream);
    k_hist<<<NEDGES / 256, 256, 0, stream>>>(eidx, cnt);
    k_scan<<<1, 256, 0, stream>>>(cnt, rowstart, cursor);
    k_fill<<<NEDGES / 256, 256, 0, stream>>>(eidx, cursor, elist);

    k_node_prep<<<NH / 256, 256, 0, stream>>>(X, Xn, Db);

    for (int l = 0; l < 2; l++) {
        const float* b1 = bs1 + (size_t)l * H;
        const float* b2 = bs2 + (size_t)l * 2 * H;
        const float* b3 = bs3 + (size_t)l * 3 * H;
        const __hip_bfloat16* W1 = W1b + (size_t)l * 4096;
        const __hip_bfloat16* W2 = W2b + (size_t)l * 32768;
        const __hip_bfloat16* W3 = W3b + (size_t)l * 98304;
        const __hip_bfloat16* Wtl = Wtb + (size_t)l * 6 * 16384;

        // Y = chan_mix(decomposed Xn)  -> bf16 planes
        k_mix<<<dim3(NATOMS / 128, 2, 9), 256, 0, stream>>>(Db, Wtl, Yb, 0);
        // edge MLP
        k_mlp<32, 128, 1><<<dim3(NEDGES / 128, 2), 256, 0, stream>>>(
            eaB, W1, b1, nullptr, ea1);
        k_mlp<128, 256, 1><<<dim3(NEDGES / 128, 4), 256, 0, stream>>>(
            ea1, W2, b2, nullptr, ea2);
        k_mlp<256, 384, 2><<<dim3(NEDGES / 128, 6), 256, 0, stream>>>(
            ea2, W3, b3, edge_weight, ea3);
        // gather + fused abnorm -> Tb (reuses Db)
        k_gather_ab<<<NH / 512, 256, 0, stream>>>(
            ea3, eidx, rowstart, elist, Yb, q, Db);
        // dX = chan_mix(T) -> bf16 planes (reuses Yb)
        k_mix<<<dim3(NATOMS / 128, 2, 9), 256, 0, stream>>>(Db, Wtl, Yb, 3);
        // final (+ fused node-prep for next layer)
        if (l == 0)
            k_final<true><<<NH / 256, 256, 0, stream>>>(Yb, Xn, q, Xout, Xn, Db);
        else
            k_final<false><<<NH / 256, 256, 0, stream>>>(Yb, Xn, q, Xout, nullptr, nullptr);
    }
}

// Round 6
// 177.216 us; speedup vs baseline: 3.5070x; 1.3073x over previous
//
#include <hip/hip_runtime.h>
#include <hip/hip_bf16.h>
#include <math.h>

#define H 128
#define R 32
#define NATOMS 2048
#define NEDGES 32768
#define NH (NATOMS * H)          // 262144 (n,h) pairs
#define NP 1152                  // 9*H: node-plane row stride (interleaved [n][9][H])
#define CUTOFF_F 4.5f
#define PI_OVER_CUTOFF 0.6981317007977318f

typedef __bf16 bf16x8 __attribute__((ext_vector_type(8)));
typedef float f32x4 __attribute__((ext_vector_type(4)));
typedef short short8 __attribute__((ext_vector_type(8)));

// ---------------------------------------------------------------------------
__device__ __forceinline__ float silu_f(float x) {
    return x / (1.f + __expf(-x));
}
__device__ __forceinline__ float b2f(unsigned short u) {
    return __uint_as_float(((unsigned)u) << 16);
}
__device__ __forceinline__ unsigned short f2b(float f) {
    __hip_bfloat16 h = __float2bfloat16(f);
    return __builtin_bit_cast(unsigned short, h);
}

// Build full 3x3 from decomposition [i0, a01, a02, a12, s00, s01, s02, s11, s12]
__device__ __forceinline__ void build_full(const float d[9], float m[9]) {
    float i0 = d[0], a01 = d[1], a02 = d[2], a12 = d[3];
    float s00 = d[4], s01 = d[5], s02 = d[6], s11 = d[7], s12 = d[8];
    float s22 = -(s00 + s11);
    m[0] = i0 + s00;  m[1] = a01 + s01;  m[2] = a02 + s02;
    m[3] = s01 - a01; m[4] = i0 + s11;   m[5] = a12 + s12;
    m[6] = s02 - a02; m[7] = s12 - a12;  m[8] = i0 + s22;
}

// ---------------------------------------------------------------------------
// One-shot cast of all fp32 params to bf16 (5 ranges fused)
#define C0 (NEDGES * R)          // edge_attr
#define C1 (2 * H * R)           // Ws1
#define C2 (2 * 2 * H * H)       // Ws2
#define C3 (2 * 3 * H * 2 * H)   // Ws3
#define C4 (2 * 6 * H * H)       // Wt
__global__ __launch_bounds__(256) void k_cast_all(
        const float* __restrict__ ea, const float* __restrict__ w1,
        const float* __restrict__ w2, const float* __restrict__ w3,
        const float* __restrict__ wt,
        __hip_bfloat16* __restrict__ oea, __hip_bfloat16* __restrict__ ow1,
        __hip_bfloat16* __restrict__ ow2, __hip_bfloat16* __restrict__ ow3,
        __hip_bfloat16* __restrict__ owt) {
    int i = blockIdx.x * 256 + threadIdx.x;
    if (i < C0) { oea[i] = __float2bfloat16(ea[i]); return; }
    i -= C0;
    if (i < C1) { ow1[i] = __float2bfloat16(w1[i]); return; }
    i -= C1;
    if (i < C2) { ow2[i] = __float2bfloat16(w2[i]); return; }
    i -= C2;
    if (i < C3) { ow3[i] = __float2bfloat16(w3[i]); return; }
    i -= C3;
    if (i < C4) { owt[i] = __float2bfloat16(wt[i]); }
}

// ---------------------------------------------------------------------------
// Node prep: X -> Xn (normalized fp32 [nh][9]) and bf16 planes Db [n][9][H]
__global__ __launch_bounds__(256) void k_node_prep(
        const float* __restrict__ X, float* __restrict__ Xn,
        __hip_bfloat16* __restrict__ Db) {
    int i = blockIdx.x * 256 + threadIdx.x;
    if (i >= NH) return;
    const float* x = X + (size_t)i * 9;
    float v[9];
    float ss = 0.f;
#pragma unroll
    for (int j = 0; j < 9; j++) { v[j] = x[j]; ss += v[j] * v[j]; }
    float inv = 1.f / (ss + 1.f);
#pragma unroll
    for (int j = 0; j < 9; j++) { v[j] *= inv; Xn[(size_t)i * 9 + j] = v[j]; }
    float i0 = (v[0] + v[4] + v[8]) * (1.f / 3.f);
    unsigned short* D = (unsigned short*)Db + (size_t)(i >> 7) * NP + (i & 127);
    D[0 * H] = f2b(i0);
    D[1 * H] = f2b(0.5f * (v[1] - v[3]));
    D[2 * H] = f2b(0.5f * (v[2] - v[6]));
    D[3 * H] = f2b(0.5f * (v[5] - v[7]));
    D[4 * H] = f2b(v[0] - i0);
    D[5 * H] = f2b(0.5f * (v[1] + v[3]));
    D[6 * H] = f2b(0.5f * (v[2] + v[6]));
    D[7 * H] = f2b(v[4] - i0);
    D[8 * H] = f2b(0.5f * (v[5] + v[7]));
}

// ---------------------------------------------------------------------------
// bf16 MFMA 128x64 tile-GEMM core for the channel mix (K=128), strided A.
struct TGm {
    static constexpr int BKm = 64;
    static constexpr int RB  = 128;        // row bytes per K-step
    static constexpr int SWZ = 7;
    static constexpr int NIT = 2;
    static constexpr int ABYTES = 128 * RB;
    static constexpr int BBYTES = 64 * RB;
    static constexpr int AISS = ABYTES / 4096;
    static constexpr int BISS = BBYTES / 4096;
    static constexpr int LDSB = ABYTES + BBYTES;
};

__device__ __forceinline__ void tile_gemm_mix(
        const __hip_bfloat16* __restrict__ A, int strideA,
        const __hip_bfloat16* __restrict__ W,
        int m0, int n0, char* lds, f32x4 acc[4][2]) {
    using T = TGm;
    const int t = threadIdx.x;
    const int lane = t & 63;
    const int w = t >> 6;

    auto stage = [&](int b, int it) {
        const int k0 = it * T::BKm;
        char* As = lds + b * T::LDSB;
        char* Bs = As + T::ABYTES;
#pragma unroll
        for (int i = 0; i < T::AISS; i++) {
            int base = (w * T::AISS + i) * 1024;
            int lin = base + lane * 16;
            int row = lin / T::RB;
            int slot = (lin % T::RB) >> 4;
            int sl = slot ^ (row & T::SWZ);
            const char* src = (const char*)(A + (size_t)(m0 + row) * strideA + k0) + sl * 16;
            __builtin_amdgcn_global_load_lds(
                (const __attribute__((address_space(1))) void*)src,
                (__attribute__((address_space(3))) void*)(As + base), 16, 0, 0);
        }
#pragma unroll
        for (int i = 0; i < T::BISS; i++) {
            int base = (w * T::BISS + i) * 1024;
            int lin = base + lane * 16;
            int row = lin / T::RB;
            int slot = (lin % T::RB) >> 4;
            int sl = slot ^ (row & T::SWZ);
            const char* src = (const char*)(W + (size_t)(n0 + row) * H + k0) + sl * 16;
            __builtin_amdgcn_global_load_lds(
                (const __attribute__((address_space(1))) void*)src,
                (__attribute__((address_space(3))) void*)(Bs + base), 16, 0, 0);
        }
    };

    auto compute = [&](int b) {
        const char* As = lds + b * T::LDSB;
        const char* Bs = As + T::ABYTES;
        const int wm = (w & 1) * 64;
        const int wn = (w >> 1) * 32;
        const int rA = wm + (lane & 15);
        const int rB = wn + (lane & 15);
        const int c = lane >> 4;
#pragma unroll
        for (int kk = 0; kk < T::BKm / 32; kk++) {
            bf16x8 av[4], bv[2];
#pragma unroll
            for (int mf = 0; mf < 4; mf++) {
                int row = rA + mf * 16;
                int sp = (kk * 4 + c) ^ (row & T::SWZ);
                av[mf] = __builtin_bit_cast(bf16x8,
                    *(const short8*)(As + row * T::RB + sp * 16));
            }
#pragma unroll
            for (int nf = 0; nf < 2; nf++) {
                int row = rB + nf * 16;
                int sp = (kk * 4 + c) ^ (row & T::SWZ);
                bv[nf] = __builtin_bit_cast(bf16x8,
                    *(const short8*)(Bs + row * T::RB + sp * 16));
            }
#pragma unroll
            for (int mf = 0; mf < 4; mf++)
#pragma unroll
                for (int nf = 0; nf < 2; nf++)
                    acc[mf][nf] = __builtin_amdgcn_mfma_f32_16x16x32_bf16(
                        av[mf], bv[nf], acc[mf][nf], 0, 0, 0);
        }
    };

    stage(0, 0);
    asm volatile("s_waitcnt vmcnt(0)" ::: "memory");
    __syncthreads();
    for (int it = 0; it < T::NIT; it++) {
        int b = it & 1;
        if (it + 1 < T::NIT) stage(b ^ 1, it + 1);
        compute(b);
        asm volatile("s_waitcnt vmcnt(0)" ::: "memory");
        __syncthreads();
    }
}

// Channel-mix: 9 interleaved planes [n][9][H] @ Wt-part [128][128] -> bf16 planes.
__global__ __launch_bounds__(256) void k_mix(
        const __hip_bfloat16* __restrict__ Db, const __hip_bfloat16* __restrict__ Wtb,
        __hip_bfloat16* __restrict__ Outp, int partOff) {
    __shared__ char lds[2 * TGm::LDSB];
    int c = blockIdx.z;
    int part = (c == 0) ? 0 : ((c < 4) ? 1 : 2);
    const __hip_bfloat16* A = Db + (size_t)c * H;
    const __hip_bfloat16* W = Wtb + (size_t)(partOff + part) * H * H;
    unsigned short* Out = (unsigned short*)Outp + (size_t)c * H;
    const int lane = threadIdx.x & 63;
    const int w = threadIdx.x >> 6;
    const int wm = (w & 1) * 64, wn = (w >> 1) * 32;
    const int m0 = blockIdx.x * 128, n0 = blockIdx.y * 64;
    f32x4 acc[4][2] = {};
    tile_gemm_mix(A, NP, W, m0, n0, lds, acc);
#pragma unroll
    for (int mf = 0; mf < 4; mf++)
#pragma unroll
        for (int r = 0; r < 4; r++) {
            int row = m0 + wm + mf * 16 + (lane >> 4) * 4 + r;
#pragma unroll
            for (int nf = 0; nf < 2; nf++) {
                int col = n0 + wn + nf * 16 + (lane & 15);
                Out[(size_t)row * NP + col] = f2b(acc[mf][nf][r]);
            }
        }
}

// ---------------------------------------------------------------------------
// Fused 3-stage edge MLP, both layers (blockIdx.z), 64 edges per block.
// act1/act2 staged in padded LDS; weights read as B-fragments from L2.
#define ETILE 64
#define PAD0 40     // sEA row stride (elements)
#define PAD1 136    // act1 row stride
#define PAD2 264    // act2 row stride
#define SA2_B (64 * PAD2 * 2)   // 33792
#define SA1_B (64 * PAD1 * 2)   // 17408

__global__ __launch_bounds__(256, 3) void k_mlp_fused(
        const __hip_bfloat16* __restrict__ eaB,
        const __hip_bfloat16* __restrict__ W1b, const __hip_bfloat16* __restrict__ W2b,
        const __hip_bfloat16* __restrict__ W3b,
        const float* __restrict__ bs1, const float* __restrict__ bs2,
        const float* __restrict__ bs3, const float* __restrict__ ew,
        __hip_bfloat16* __restrict__ ea3g) {
    const int l = blockIdx.z;
    const __hip_bfloat16* W1 = W1b + (size_t)l * (H * R);
    const __hip_bfloat16* W2 = W2b + (size_t)l * (2 * H * H);
    const __hip_bfloat16* W3 = W3b + (size_t)l * (3 * H * 2 * H);
    const float* b1 = bs1 + (size_t)l * H;
    const float* b2 = bs2 + (size_t)l * 2 * H;
    const float* b3 = bs3 + (size_t)l * 3 * H;
    unsigned short* outp = (unsigned short*)ea3g + (size_t)l * NEDGES * 384;
    const int e0 = blockIdx.x * ETILE;

    __shared__ char smem[SA2_B + SA1_B + 256 + 16];
    unsigned short* sA2 = (unsigned short*)smem;            // [64][PAD2]
    unsigned short* sEA = (unsigned short*)smem;            // [64][PAD0] (overlaps sA2; dead before sA2 written)
    unsigned short* sA1 = (unsigned short*)(smem + SA2_B);  // [64][PAD1]
    float* sEW = (float*)(smem + SA2_B + SA1_B);

    const int t = threadIdx.x;
    const int lane = t & 63;
    const int w = t >> 6;
    const int q = lane >> 4;     // k-chunk / row-subgroup
    const int li = lane & 15;

    // stage edge_attr tile [64][32] + ew tile
    {
        int row = t >> 2, c8 = t & 3;
        *(uint4*)(sEA + row * PAD0 + c8 * 8) =
            *(const uint4*)((const unsigned short*)eaB + (size_t)(e0 + row) * R + c8 * 8);
        if (t < ETILE) sEW[t] = ew[e0 + t];
    }
    __syncthreads();

    // ---- GEMM1: [64,32] @ W1[128,32]^T -> act1 [64,128], silu ----
    {
        f32x4 acc1[4][2] = {};
        bf16x8 bv[2];
#pragma unroll
        for (int nf = 0; nf < 2; nf++) {
            int col = w * 32 + nf * 16 + li;
            bv[nf] = __builtin_bit_cast(bf16x8,
                *(const short8*)((const unsigned short*)W1 + (size_t)col * R + q * 8));
        }
#pragma unroll
        for (int mf = 0; mf < 4; mf++) {
            int row = mf * 16 + li;
            bf16x8 av = __builtin_bit_cast(bf16x8,
                *(const short8*)(sEA + row * PAD0 + q * 8));
#pragma unroll
            for (int nf = 0; nf < 2; nf++)
                acc1[mf][nf] = __builtin_amdgcn_mfma_f32_16x16x32_bf16(
                    av, bv[nf], acc1[mf][nf], 0, 0, 0);
        }
        float bb[2];
#pragma unroll
        for (int nf = 0; nf < 2; nf++) bb[nf] = b1[w * 32 + nf * 16 + li];
        __syncthreads();   // all reads of sEA done before (act2 region reused later)
#pragma unroll
        for (int mf = 0; mf < 4; mf++)
#pragma unroll
            for (int r = 0; r < 4; r++) {
                int row = mf * 16 + q * 4 + r;
#pragma unroll
                for (int nf = 0; nf < 2; nf++) {
                    int col = w * 32 + nf * 16 + li;
                    sA1[row * PAD1 + col] = f2b(silu_f(acc1[mf][nf][r] + bb[nf]));
                }
            }
    }
    __syncthreads();

    // ---- GEMM2: act1 [64,128] @ W2[256,128]^T -> act2 [64,256], silu ----
    {
        f32x4 acc2[4][4] = {};
#pragma unroll
        for (int ks = 0; ks < 4; ks++) {
            bf16x8 bv[4];
#pragma unroll
            for (int nf = 0; nf < 4; nf++) {
                int col = w * 64 + nf * 16 + li;
                bv[nf] = __builtin_bit_cast(bf16x8,
                    *(const short8*)((const unsigned short*)W2 + (size_t)col * H + ks * 32 + q * 8));
            }
#pragma unroll
            for (int mf = 0; mf < 4; mf++) {
                int row = mf * 16 + li;
                bf16x8 av = __builtin_bit_cast(bf16x8,
                    *(const short8*)(sA1 + row * PAD1 + ks * 32 + q * 8));
#pragma unroll
                for (int nf = 0; nf < 4; nf++)
                    acc2[mf][nf] = __builtin_amdgcn_mfma_f32_16x16x32_bf16(
                        av, bv[nf], acc2[mf][nf], 0, 0, 0);
            }
        }
        float bb[4];
#pragma unroll
        for (int nf = 0; nf < 4; nf++) bb[nf] = b2[w * 64 + nf * 16 + li];
        __syncthreads();   // GEMM1's sEA reads long done; safe to write sA2 region
#pragma unroll
        for (int mf = 0; mf < 4; mf++)
#pragma unroll
            for (int r = 0; r < 4; r++) {
                int row = mf * 16 + q * 4 + r;
#pragma unroll
                for (int nf = 0; nf < 4; nf++) {
                    int col = w * 64 + nf * 16 + li;
                    sA2[row * PAD2 + col] = f2b(silu_f(acc2[mf][nf][r] + bb[nf]));
                }
            }
    }
    __syncthreads();

    // ---- GEMM3: act2 [64,256] @ W3[384,256]^T -> [64,384], silu, cutoff ----
    {
        f32x4 acc3[4][6] = {};
#pragma unroll
        for (int ks = 0; ks < 8; ks++) {
            bf16x8 bv[6];
#pragma unroll
            for (int nf = 0; nf < 6; nf++) {
                int col = w * 96 + nf * 16 + li;
                bv[nf] = __builtin_bit_cast(bf16x8,
                    *(const short8*)((const unsigned short*)W3 + (size_t)col * (2 * H) + ks * 32 + q * 8));
            }
#pragma unroll
            for (int mf = 0; mf < 4; mf++) {
                int row = mf * 16 + li;
                bf16x8 av = __builtin_bit_cast(bf16x8,
                    *(const short8*)(sA2 + row * PAD2 + ks * 32 + q * 8));
#pragma unroll
                for (int nf = 0; nf < 6; nf++)
                    acc3[mf][nf] = __builtin_amdgcn_mfma_f32_16x16x32_bf16(
                        av, bv[nf], acc3[mf][nf], 0, 0, 0);
            }
        }
        float bb[6];
#pragma unroll
        for (int nf = 0; nf < 6; nf++) bb[nf] = b3[w * 96 + nf * 16 + li];
#pragma unroll
        for (int mf = 0; mf < 4; mf++)
#pragma unroll
            for (int r = 0; r < 4; r++) {
                int row = mf * 16 + q * 4 + r;
                float wv = sEW[row];
                float cs = (wv < CUTOFF_F) ? 0.5f * (__cosf(wv * PI_OVER_CUTOFF) + 1.f) : 0.f;
#pragma unroll
                for (int nf = 0; nf < 6; nf++) {
                    int col = w * 96 + nf * 16 + li;
                    float x = silu_f(acc3[mf][nf][r] + bb[nf]) * cs;
                    outp[(size_t)(e0 + row) * 384 + col] = f2b(x);
                }
            }
    }
}

// ---------------------------------------------------------------------------
// CSR build (once; edge_index is static across layers)
__global__ __launch_bounds__(256) void k_hist(
        const int* __restrict__ eidx, int* __restrict__ cnt) {
    int e = blockIdx.x * 256 + threadIdx.x;
    if (e < NEDGES) atomicAdd(&cnt[eidx[e]], 1);
}

__global__ __launch_bounds__(256) void k_scan(
        const int* __restrict__ cnt, int* __restrict__ rowstart,
        int* __restrict__ cursor) {
    __shared__ int partial[256];
    int t = threadIdx.x;
    int loc[8];
    int run = 0;
#pragma unroll
    for (int j = 0; j < 8; j++) {
        int v = cnt[t * 8 + j];
        loc[j] = run; run += v;
    }
    partial[t] = run;
    __syncthreads();
    if (t == 0) {
        int acc = 0;
        for (int i = 0; i < 256; i++) { int v = partial[i]; partial[i] = acc; acc += v; }
        rowstart[2048] = acc;
    }
    __syncthreads();
    int base = partial[t];
#pragma unroll
    for (int j = 0; j < 8; j++) {
        rowstart[t * 8 + j] = base + loc[j];
        cursor[t * 8 + j] = base + loc[j];
    }
}

__global__ __launch_bounds__(256) void k_fill(
        const int* __restrict__ eidx, int* __restrict__ cursor,
        int* __restrict__ elist) {
    int e = blockIdx.x * 256 + threadIdx.x;
    if (e >= NEDGES) return;
    int src = eidx[e];
    int pos = atomicAdd(&cursor[src], 1);
    elist[pos] = e;
}

// ---------------------------------------------------------------------------
// Gather + fused abnorm. One wave per node, one thread per h-pair.
// ea natural [E][384] (col = h*3+comp); Y/T interleaved [n][9][H] bf16.
__global__ __launch_bounds__(256) void k_gather_ab(
        const __hip_bfloat16* __restrict__ ea,
        const int* __restrict__ eidx,
        const int* __restrict__ rowstart, const int* __restrict__ elist,
        const __hip_bfloat16* __restrict__ Yb, const float* __restrict__ q,
        __hip_bfloat16* __restrict__ Tb) {
    int gid = blockIdx.x * 256 + threadIdx.x;   // NH/2 threads
    int n = gid >> 6;
    int h0 = (gid & 63) << 1;
    int beg = rowstart[n], end = rowstart[n + 1];
    const unsigned short* Y = (const unsigned short*)Yb;
    float acc[9][2];
#pragma unroll
    for (int c = 0; c < 9; c++) { acc[c][0] = 0.f; acc[c][1] = 0.f; }
    for (int idx = beg; idx < end; ++idx) {
        int e = elist[idx];
        int dst = eidx[NEDGES + e];
        const unsigned short* eap = (const unsigned short*)ea + (size_t)e * 384 + h0 * 3;
        unsigned u0 = *(const unsigned*)(eap);
        unsigned u1 = *(const unsigned*)(eap + 2);
        unsigned u2 = *(const unsigned*)(eap + 4);
        float w0a = b2f(u0 & 0xffff), w1a = b2f(u0 >> 16);
        float w2a = b2f(u1 & 0xffff), w0b = b2f(u1 >> 16);
        float w1b = b2f(u2 & 0xffff), w2b = b2f(u2 >> 16);
        const unsigned short* yp = Y + (size_t)dst * NP + h0;
        ushort2 y;
        y = *(const ushort2*)(yp + 0 * H); acc[0][0] += w0a * b2f(y.x); acc[0][1] += w0b * b2f(y.y);
        y = *(const ushort2*)(yp + 1 * H); acc[1][0] += w1a * b2f(y.x); acc[1][1] += w1b * b2f(y.y);
        y = *(const ushort2*)(yp + 2 * H); acc[2][0] += w1a * b2f(y.x); acc[2][1] += w1b * b2f(y.y);
        y = *(const ushort2*)(yp + 3 * H); acc[3][0] += w1a * b2f(y.x); acc[3][1] += w1b * b2f(y.y);
#pragma unroll
        for (int c = 4; c < 9; c++) {
            y = *(const ushort2*)(yp + c * H);
            acc[c][0] += w2a * b2f(y.x); acc[c][1] += w2b * b2f(y.y);
        }
    }
    // fused abnorm for the two h columns
    const unsigned short* yp = Y + (size_t)n * NP + h0;
    float scale = 1.f + 0.1f * q[n];
    float yd2[9][2];
#pragma unroll
    for (int c = 0; c < 9; c++) {
        ushort2 y = *(const ushort2*)(yp + (size_t)c * H);
        yd2[c][0] = b2f(y.x); yd2[c][1] = b2f(y.y);
    }
    unsigned short outw[9][2];
#pragma unroll
    for (int col = 0; col < 2; col++) {
        float md[9], yd[9];
#pragma unroll
        for (int c = 0; c < 9; c++) { md[c] = acc[c][col]; yd[c] = yd2[c][col]; }
        float m[9], yf[9];
        build_full(md, m);
        build_full(yd, yf);
        float ab[9];
#pragma unroll
        for (int ii = 0; ii < 3; ii++)
#pragma unroll
            for (int jj = 0; jj < 3; jj++) {
                float s = 0.f;
#pragma unroll
                for (int kk = 0; kk < 3; kk++)
                    s += m[ii * 3 + kk] * yf[kk * 3 + jj] + yf[ii * 3 + kk] * m[kk * 3 + jj];
                ab[ii * 3 + jj] = s;
            }
        float nrm = 0.f;
#pragma unroll
        for (int j = 0; j < 9; j++) { ab[j] *= scale; nrm += ab[j] * ab[j]; }
        float inv = 1.f / (nrm + 1.f);
        float tr3 = (ab[0] + ab[4] + ab[8]) * (1.f / 3.f);
        outw[0][col] = f2b(tr3 * inv);
        outw[1][col] = f2b(0.5f * (ab[1] - ab[3]) * inv);
        outw[2][col] = f2b(0.5f * (ab[2] - ab[6]) * inv);
        outw[3][col] = f2b(0.5f * (ab[5] - ab[7]) * inv);
        outw[4][col] = f2b((ab[0] - tr3) * inv);
        outw[5][col] = f2b(0.5f * (ab[1] + ab[3]) * inv);
        outw[6][col] = f2b(0.5f * (ab[2] + ab[6]) * inv);
        outw[7][col] = f2b((ab[4] - tr3) * inv);
        outw[8][col] = f2b(0.5f * (ab[5] + ab[7]) * inv);
    }
    unsigned short* T = (unsigned short*)Tb + (size_t)n * NP + h0;
#pragma unroll
    for (int c = 0; c < 9; c++) {
        ushort2 o; o.x = outw[c][0]; o.y = outw[c][1];
        *(ushort2*)(T + (size_t)c * H) = o;
    }
}

// ---------------------------------------------------------------------------
// Final: Xout = Xn + dX + (1+0.1q)*dX@dX.  dX interleaved bf16 [n][9][H].
// PREP: also normalize+decompose Xout into Xn (fp32) and Db (bf16) for next layer.
template <bool PREP>
__global__ __launch_bounds__(256) void k_final(
        const __hip_bfloat16* __restrict__ dXb, const float* __restrict__ Xn,
        const float* __restrict__ q, float* __restrict__ Xout,
        float* __restrict__ XnW, __hip_bfloat16* __restrict__ Db) {
    int i = blockIdx.x * 256 + threadIdx.x;
    if (i >= NH) return;
    const unsigned short* dX = (const unsigned short*)dXb + (size_t)(i >> 7) * NP + (i & 127);
    float dd[9];
#pragma unroll
    for (int c = 0; c < 9; c++) dd[c] = b2f(dX[(size_t)c * H]);
    float dx[9];
    build_full(dd, dx);
    float scale = 1.f + 0.1f * q[i >> 7];
    float out[9];
#pragma unroll
    for (int ii = 0; ii < 3; ii++)
#pragma unroll
        for (int jj = 0; jj < 3; jj++) {
            float s = 0.f;
#pragma unroll
            for (int kk = 0; kk < 3; kk++)
                s += dx[ii * 3 + kk] * dx[kk * 3 + jj];
            out[ii * 3 + jj] = Xn[(size_t)i * 9 + ii * 3 + jj] + dx[ii * 3 + jj] + scale * s;
        }
#pragma unroll
    for (int j = 0; j < 9; j++) Xout[(size_t)i * 9 + j] = out[j];
    if (PREP) {
        float ss = 0.f;
#pragma unroll
        for (int j = 0; j < 9; j++) ss += out[j] * out[j];
        float inv = 1.f / (ss + 1.f);
        float v[9];
#pragma unroll
        for (int j = 0; j < 9; j++) { v[j] = out[j] * inv; XnW[(size_t)i * 9 + j] = v[j]; }
        float i0 = (v[0] + v[4] + v[8]) * (1.f / 3.f);
        unsigned short* D = (unsigned short*)Db + (size_t)(i >> 7) * NP + (i & 127);
        D[0 * H] = f2b(i0);
        D[1 * H] = f2b(0.5f * (v[1] - v[3]));
        D[2 * H] = f2b(0.5f * (v[2] - v[6]));
        D[3 * H] = f2b(0.5f * (v[5] - v[7]));
        D[4 * H] = f2b(v[0] - i0);
        D[5 * H] = f2b(0.5f * (v[1] + v[3]));
        D[6 * H] = f2b(0.5f * (v[2] + v[6]));
        D[7 * H] = f2b(v[4] - i0);
        D[8 * H] = f2b(0.5f * (v[5] + v[7]));
    }
}

// ---------------------------------------------------------------------------
extern "C" void kernel_launch(void* const* d_in, const int* in_sizes, int n_in,
                              void* d_out, int out_size, void* d_ws, size_t ws_size,
                              hipStream_t stream) {
    const float* X          = (const float*)d_in[0];
    const float* edge_attr  = (const float*)d_in[1];
    const float* edge_weight= (const float*)d_in[2];
    const float* q          = (const float*)d_in[3];
    const float* Ws1        = (const float*)d_in[4];
    const float* bs1        = (const float*)d_in[5];
    const float* Ws2        = (const float*)d_in[6];
    const float* bs2        = (const float*)d_in[7];
    const float* Ws3        = (const float*)d_in[8];
    const float* bs3        = (const float*)d_in[9];
    const float* Wt         = (const float*)d_in[10];
    const int*   eidx       = (const int*)d_in[11];
    float* Xout = (float*)d_out;

    char* p = (char*)d_ws;
    auto alloc = [&](size_t bytes) -> char* {
        char* r = p; p += (bytes + 255) & ~(size_t)255; return r;
    };
    size_t nodeBytes = (size_t)NH * 9 * sizeof(float);
    float* Xn   = (float*)alloc(nodeBytes);
    __hip_bfloat16* Db = (__hip_bfloat16*)alloc((size_t)NH * 9 * 2);  // D / T planes
    __hip_bfloat16* Yb = (__hip_bfloat16*)alloc((size_t)NH * 9 * 2);  // Y, then dX
    __hip_bfloat16* eaB = (__hip_bfloat16*)alloc((size_t)C0 * 2);
    __hip_bfloat16* W1b = (__hip_bfloat16*)alloc((size_t)C1 * 2);
    __hip_bfloat16* W2b = (__hip_bfloat16*)alloc((size_t)C2 * 2);
    __hip_bfloat16* W3b = (__hip_bfloat16*)alloc((size_t)C3 * 2);
    __hip_bfloat16* Wtb = (__hip_bfloat16*)alloc((size_t)C4 * 2);
    __hip_bfloat16* ea3g = (__hip_bfloat16*)alloc((size_t)2 * NEDGES * 384 * 2);
    int* cnt      = (int*)alloc(2048 * 4);
    int* rowstart = (int*)alloc(2049 * 4);
    int* cursor   = (int*)alloc(2048 * 4);
    int* elist    = (int*)alloc(NEDGES * 4);

    // one-time bf16 casts (fused)
    k_cast_all<<<(C0 + C1 + C2 + C3 + C4) / 256, 256, 0, stream>>>(
        edge_attr, Ws1, Ws2, Ws3, Wt, eaB, W1b, W2b, W3b, Wtb);

    // CSR once (edge_index static across layers)
    hipMemsetAsync(cnt, 0, 2048 * sizeof(int), stream);
    k_hist<<<NEDGES / 256, 256, 0, stream>>>(eidx, cnt);
    k_scan<<<1, 256, 0, stream>>>(cnt, rowstart, cursor);
    k_fill<<<NEDGES / 256, 256, 0, stream>>>(eidx, cursor, elist);

    k_node_prep<<<NH / 256, 256, 0, stream>>>(X, Xn, Db);

    // edge MLP for BOTH layers in one launch (independent of X)
    k_mlp_fused<<<dim3(NEDGES / ETILE, 1, 2), 256, 0, stream>>>(
        eaB, W1b, W2b, W3b, bs1, bs2, bs3, edge_weight, ea3g);

    for (int l = 0; l < 2; l++) {
        const __hip_bfloat16* Wtl = Wtb + (size_t)l * 6 * H * H;
        const __hip_bfloat16* ea3 = ea3g + (size_t)l * NEDGES * 384;

        // Y = chan_mix(decomposed Xn) -> bf16 interleaved planes
        k_mix<<<dim3(NATOMS / 128, 2, 9), 256, 0, stream>>>(Db, Wtl, Yb, 0);
        // gather + fused abnorm -> Tb (reuses Db)
        k_gather_ab<<<NH / 512, 256, 0, stream>>>(
            ea3, eidx, rowstart, elist, Yb, q, Db);
        // dX = chan_mix(T) -> bf16 interleaved planes (reuses Yb)
        k_mix<<<dim3(NATOMS / 128, 2, 9), 256, 0, stream>>>(Db, Wtl, Yb, 3);
        // final (+ fused node-prep for next layer)
        if (l == 0)
            k_final<true><<<NH / 256, 256, 0, stream>>>(Yb, Xn, q, Xout, Xn, Db);
        else
            k_final<false><<<NH / 256, 256, 0, stream>>>(Yb, Xn, q, Xout, nullptr, nullptr);
    }
}

// Round 7
// 166.361 us; speedup vs baseline: 3.7359x; 1.0653x over previous
//
#include <hip/hip_runtime.h>
#include <hip/hip_bf16.h>
#include <math.h>

#define H 128
#define R 32
#define NATOMS 2048
#define NEDGES 32768
#define NH (NATOMS * H)          // 262144 (n,h) pairs
#define NP 1152                  // 9*H: node-plane row stride (interleaved [n][9][H])
#define CUTOFF_F 4.5f
#define PI_OVER_CUTOFF 0.6981317007977318f

typedef __bf16 bf16x8 __attribute__((ext_vector_type(8)));
typedef float f32x4 __attribute__((ext_vector_type(4)));
typedef short short8 __attribute__((ext_vector_type(8)));

// ---------------------------------------------------------------------------
__device__ __forceinline__ float silu_f(float x) {
    return x / (1.f + __expf(-x));
}
__device__ __forceinline__ float b2f(unsigned short u) {
    return __uint_as_float(((unsigned)u) << 16);
}
__device__ __forceinline__ unsigned short f2b(float f) {
    __hip_bfloat16 h = __float2bfloat16(f);
    return __builtin_bit_cast(unsigned short, h);
}

// Build full 3x3 from decomposition [i0, a01, a02, a12, s00, s01, s02, s11, s12]
__device__ __forceinline__ void build_full(const float d[9], float m[9]) {
    float i0 = d[0], a01 = d[1], a02 = d[2], a12 = d[3];
    float s00 = d[4], s01 = d[5], s02 = d[6], s11 = d[7], s12 = d[8];
    float s22 = -(s00 + s11);
    m[0] = i0 + s00;  m[1] = a01 + s01;  m[2] = a02 + s02;
    m[3] = s01 - a01; m[4] = i0 + s11;   m[5] = a12 + s12;
    m[6] = s02 - a02; m[7] = s12 - a12;  m[8] = i0 + s22;
}

// ---------------------------------------------------------------------------
// One-shot cast of all fp32 params to bf16 (5 ranges fused)
#define C0 (NEDGES * R)          // edge_attr
#define C1 (2 * H * R)           // Ws1
#define C2 (2 * 2 * H * H)       // Ws2
#define C3 (2 * 3 * H * 2 * H)   // Ws3
#define C4 (2 * 6 * H * H)       // Wt
__global__ __launch_bounds__(256) void k_cast_all(
        const float* __restrict__ ea, const float* __restrict__ w1,
        const float* __restrict__ w2, const float* __restrict__ w3,
        const float* __restrict__ wt,
        __hip_bfloat16* __restrict__ oea, __hip_bfloat16* __restrict__ ow1,
        __hip_bfloat16* __restrict__ ow2, __hip_bfloat16* __restrict__ ow3,
        __hip_bfloat16* __restrict__ owt) {
    int i = blockIdx.x * 256 + threadIdx.x;
    if (i < C0) { oea[i] = __float2bfloat16(ea[i]); return; }
    i -= C0;
    if (i < C1) { ow1[i] = __float2bfloat16(w1[i]); return; }
    i -= C1;
    if (i < C2) { ow2[i] = __float2bfloat16(w2[i]); return; }
    i -= C2;
    if (i < C3) { ow3[i] = __float2bfloat16(w3[i]); return; }
    i -= C3;
    if (i < C4) { owt[i] = __float2bfloat16(wt[i]); }
}

// ---------------------------------------------------------------------------
// Node prep: X -> Xn (normalized fp32 [nh][9]) and bf16 planes Db [n][9][H]
__global__ __launch_bounds__(256) void k_node_prep(
        const float* __restrict__ X, float* __restrict__ Xn,
        __hip_bfloat16* __restrict__ Db) {
    int i = blockIdx.x * 256 + threadIdx.x;
    if (i >= NH) return;
    const float* x = X + (size_t)i * 9;
    float v[9];
    float ss = 0.f;
#pragma unroll
    for (int j = 0; j < 9; j++) { v[j] = x[j]; ss += v[j] * v[j]; }
    float inv = 1.f / (ss + 1.f);
#pragma unroll
    for (int j = 0; j < 9; j++) { v[j] *= inv; Xn[(size_t)i * 9 + j] = v[j]; }
    float i0 = (v[0] + v[4] + v[8]) * (1.f / 3.f);
    unsigned short* D = (unsigned short*)Db + (size_t)(i >> 7) * NP + (i & 127);
    D[0 * H] = f2b(i0);
    D[1 * H] = f2b(0.5f * (v[1] - v[3]));
    D[2 * H] = f2b(0.5f * (v[2] - v[6]));
    D[3 * H] = f2b(0.5f * (v[5] - v[7]));
    D[4 * H] = f2b(v[0] - i0);
    D[5 * H] = f2b(0.5f * (v[1] + v[3]));
    D[6 * H] = f2b(0.5f * (v[2] + v[6]));
    D[7 * H] = f2b(v[4] - i0);
    D[8 * H] = f2b(0.5f * (v[5] + v[7]));
}

// ---------------------------------------------------------------------------
// bf16 MFMA 128x64 tile-GEMM core for the channel mix (K=128), strided A.
struct TGm {
    static constexpr int BKm = 64;
    static constexpr int RB  = 128;        // row bytes per K-step
    static constexpr int SWZ = 7;
    static constexpr int NIT = 2;
    static constexpr int ABYTES = 128 * RB;
    static constexpr int BBYTES = 64 * RB;
    static constexpr int AISS = ABYTES / 4096;
    static constexpr int BISS = BBYTES / 4096;
    static constexpr int LDSB = ABYTES + BBYTES;
};

__device__ __forceinline__ void tile_gemm_mix(
        const __hip_bfloat16* __restrict__ A, int strideA,
        const __hip_bfloat16* __restrict__ W,
        int m0, int n0, char* lds, f32x4 acc[4][2]) {
    using T = TGm;
    const int t = threadIdx.x;
    const int lane = t & 63;
    const int w = t >> 6;

    auto stage = [&](int b, int it) {
        const int k0 = it * T::BKm;
        char* As = lds + b * T::LDSB;
        char* Bs = As + T::ABYTES;
#pragma unroll
        for (int i = 0; i < T::AISS; i++) {
            int base = (w * T::AISS + i) * 1024;
            int lin = base + lane * 16;
            int row = lin / T::RB;
            int slot = (lin % T::RB) >> 4;
            int sl = slot ^ (row & T::SWZ);
            const char* src = (const char*)(A + (size_t)(m0 + row) * strideA + k0) + sl * 16;
            __builtin_amdgcn_global_load_lds(
                (const __attribute__((address_space(1))) void*)src,
                (__attribute__((address_space(3))) void*)(As + base), 16, 0, 0);
        }
#pragma unroll
        for (int i = 0; i < T::BISS; i++) {
            int base = (w * T::BISS + i) * 1024;
            int lin = base + lane * 16;
            int row = lin / T::RB;
            int slot = (lin % T::RB) >> 4;
            int sl = slot ^ (row & T::SWZ);
            const char* src = (const char*)(W + (size_t)(n0 + row) * H + k0) + sl * 16;
            __builtin_amdgcn_global_load_lds(
                (const __attribute__((address_space(1))) void*)src,
                (__attribute__((address_space(3))) void*)(Bs + base), 16, 0, 0);
        }
    };

    auto compute = [&](int b) {
        const char* As = lds + b * T::LDSB;
        const char* Bs = As + T::ABYTES;
        const int wm = (w & 1) * 64;
        const int wn = (w >> 1) * 32;
        const int rA = wm + (lane & 15);
        const int rB = wn + (lane & 15);
        const int c = lane >> 4;
#pragma unroll
        for (int kk = 0; kk < T::BKm / 32; kk++) {
            bf16x8 av[4], bv[2];
#pragma unroll
            for (int mf = 0; mf < 4; mf++) {
                int row = rA + mf * 16;
                int sp = (kk * 4 + c) ^ (row & T::SWZ);
                av[mf] = __builtin_bit_cast(bf16x8,
                    *(const short8*)(As + row * T::RB + sp * 16));
            }
#pragma unroll
            for (int nf = 0; nf < 2; nf++) {
                int row = rB + nf * 16;
                int sp = (kk * 4 + c) ^ (row & T::SWZ);
                bv[nf] = __builtin_bit_cast(bf16x8,
                    *(const short8*)(Bs + row * T::RB + sp * 16));
            }
#pragma unroll
            for (int mf = 0; mf < 4; mf++)
#pragma unroll
                for (int nf = 0; nf < 2; nf++)
                    acc[mf][nf] = __builtin_amdgcn_mfma_f32_16x16x32_bf16(
                        av[mf], bv[nf], acc[mf][nf], 0, 0, 0);
        }
    };

    stage(0, 0);
    asm volatile("s_waitcnt vmcnt(0)" ::: "memory");
    __syncthreads();
    for (int it = 0; it < T::NIT; it++) {
        int b = it & 1;
        if (it + 1 < T::NIT) stage(b ^ 1, it + 1);
        compute(b);
        asm volatile("s_waitcnt vmcnt(0)" ::: "memory");
        __syncthreads();
    }
}

// Channel-mix: 9 interleaved planes [n][9][H] @ Wt-part [128][128] -> bf16 planes.
__global__ __launch_bounds__(256) void k_mix(
        const __hip_bfloat16* __restrict__ Db, const __hip_bfloat16* __restrict__ Wtb,
        __hip_bfloat16* __restrict__ Outp, int partOff) {
    __shared__ char lds[2 * TGm::LDSB];
    int c = blockIdx.z;
    int part = (c == 0) ? 0 : ((c < 4) ? 1 : 2);
    const __hip_bfloat16* A = Db + (size_t)c * H;
    const __hip_bfloat16* W = Wtb + (size_t)(partOff + part) * H * H;
    unsigned short* Out = (unsigned short*)Outp + (size_t)c * H;
    const int lane = threadIdx.x & 63;
    const int w = threadIdx.x >> 6;
    const int wm = (w & 1) * 64, wn = (w >> 1) * 32;
    const int m0 = blockIdx.x * 128, n0 = blockIdx.y * 64;
    f32x4 acc[4][2] = {};
    tile_gemm_mix(A, NP, W, m0, n0, lds, acc);
#pragma unroll
    for (int mf = 0; mf < 4; mf++)
#pragma unroll
        for (int r = 0; r < 4; r++) {
            int row = m0 + wm + mf * 16 + (lane >> 4) * 4 + r;
#pragma unroll
            for (int nf = 0; nf < 2; nf++) {
                int col = n0 + wn + nf * 16 + (lane & 15);
                Out[(size_t)row * NP + col] = f2b(acc[mf][nf][r]);
            }
        }
}

// ---------------------------------------------------------------------------
// Fused 3-stage edge MLP, both layers (blockIdx.z), 64 edges per block.
// act1/act2 staged in padded LDS; weight B-fragments register-double-buffered
// across ks phases so L2 latency hides under the MFMA cluster.
#define ETILE 64
#define PAD0 40     // sEA row stride (elements)
#define PAD1 136    // act1 row stride
#define PAD2 264    // act2 row stride
#define SA2_B (64 * PAD2 * 2)   // 33792
#define SA1_B (64 * PAD1 * 2)   // 17408

__global__ __launch_bounds__(256, 3) void k_mlp_fused(
        const __hip_bfloat16* __restrict__ eaB,
        const __hip_bfloat16* __restrict__ W1b, const __hip_bfloat16* __restrict__ W2b,
        const __hip_bfloat16* __restrict__ W3b,
        const float* __restrict__ bs1, const float* __restrict__ bs2,
        const float* __restrict__ bs3, const float* __restrict__ ew,
        __hip_bfloat16* __restrict__ ea3g) {
    const int l = blockIdx.z;
    const unsigned short* W1 = (const unsigned short*)W1b + (size_t)l * (H * R);
    const unsigned short* W2 = (const unsigned short*)W2b + (size_t)l * (2 * H * H);
    const unsigned short* W3 = (const unsigned short*)W3b + (size_t)l * (3 * H * 2 * H);
    const float* b1 = bs1 + (size_t)l * H;
    const float* b2 = bs2 + (size_t)l * 2 * H;
    const float* b3 = bs3 + (size_t)l * 3 * H;
    unsigned short* outp = (unsigned short*)ea3g + (size_t)l * NEDGES * 384;
    const int e0 = blockIdx.x * ETILE;

    __shared__ char smem[SA2_B + SA1_B + 256 + 16];
    unsigned short* sA2 = (unsigned short*)smem;            // [64][PAD2]
    unsigned short* sEA = (unsigned short*)smem;            // [64][PAD0] (overlaps sA2; dead before sA2 written)
    unsigned short* sA1 = (unsigned short*)(smem + SA2_B);  // [64][PAD1]
    float* sEW = (float*)(smem + SA2_B + SA1_B);

    const int t = threadIdx.x;
    const int lane = t & 63;
    const int w = t >> 6;
    const int q = lane >> 4;     // k-chunk / row-subgroup
    const int li = lane & 15;

    // stage edge_attr tile [64][32] + ew tile
    {
        int row = t >> 2, c8 = t & 3;
        *(uint4*)(sEA + row * PAD0 + c8 * 8) =
            *(const uint4*)((const unsigned short*)eaB + (size_t)(e0 + row) * R + c8 * 8);
        if (t < ETILE) sEW[t] = ew[e0 + t];
    }
    __syncthreads();

    // ---- GEMM1: [64,32] @ W1[128,32]^T -> act1 [64,128], silu ----
    {
        f32x4 acc1[4][2] = {};
        bf16x8 bv[2];
#pragma unroll
        for (int nf = 0; nf < 2; nf++) {
            int col = w * 32 + nf * 16 + li;
            bv[nf] = __builtin_bit_cast(bf16x8,
                *(const short8*)(W1 + (size_t)col * R + q * 8));
        }
#pragma unroll
        for (int mf = 0; mf < 4; mf++) {
            int row = mf * 16 + li;
            bf16x8 av = __builtin_bit_cast(bf16x8,
                *(const short8*)(sEA + row * PAD0 + q * 8));
#pragma unroll
            for (int nf = 0; nf < 2; nf++)
                acc1[mf][nf] = __builtin_amdgcn_mfma_f32_16x16x32_bf16(
                    av, bv[nf], acc1[mf][nf], 0, 0, 0);
        }
        float bb[2];
#pragma unroll
        for (int nf = 0; nf < 2; nf++) bb[nf] = b1[w * 32 + nf * 16 + li];
        __syncthreads();   // all reads of sEA done before (act2 region reused later)
#pragma unroll
        for (int mf = 0; mf < 4; mf++)
#pragma unroll
            for (int r = 0; r < 4; r++) {
                int row = mf * 16 + q * 4 + r;
#pragma unroll
                for (int nf = 0; nf < 2; nf++) {
                    int col = w * 32 + nf * 16 + li;
                    sA1[row * PAD1 + col] = f2b(silu_f(acc1[mf][nf][r] + bb[nf]));
                }
            }
    }
    __syncthreads();

    // ---- GEMM2: act1 [64,128] @ W2[256,128]^T -> act2 [64,256], silu ----
    // weight fragments double-buffered in registers across the 4 ks phases.
    {
        f32x4 acc2[4][4] = {};
        bf16x8 b2v[2][4];
#pragma unroll
        for (int nf = 0; nf < 4; nf++)
            b2v[0][nf] = __builtin_bit_cast(bf16x8,
                *(const short8*)(W2 + (size_t)(w * 64 + nf * 16 + li) * H + q * 8));
#pragma unroll
        for (int ks = 0; ks < 4; ks++) {
            const int cur = ks & 1;
            if (ks < 3) {
#pragma unroll
                for (int nf = 0; nf < 4; nf++)
                    b2v[cur ^ 1][nf] = __builtin_bit_cast(bf16x8,
                        *(const short8*)(W2 + (size_t)(w * 64 + nf * 16 + li) * H
                                         + (ks + 1) * 32 + q * 8));
            }
            bf16x8 av[4];
#pragma unroll
            for (int mf = 0; mf < 4; mf++)
                av[mf] = __builtin_bit_cast(bf16x8,
                    *(const short8*)(sA1 + (mf * 16 + li) * PAD1 + ks * 32 + q * 8));
            __builtin_amdgcn_s_setprio(1);
#pragma unroll
            for (int mf = 0; mf < 4; mf++)
#pragma unroll
                for (int nf = 0; nf < 4; nf++)
                    acc2[mf][nf] = __builtin_amdgcn_mfma_f32_16x16x32_bf16(
                        av[mf], b2v[cur][nf], acc2[mf][nf], 0, 0, 0);
            __builtin_amdgcn_s_setprio(0);
        }
        float bb[4];
#pragma unroll
        for (int nf = 0; nf < 4; nf++) bb[nf] = b2[w * 64 + nf * 16 + li];
        __syncthreads();   // GEMM1's sEA reads long done; safe to write sA2 region
#pragma unroll
        for (int mf = 0; mf < 4; mf++)
#pragma unroll
            for (int r = 0; r < 4; r++) {
                int row = mf * 16 + q * 4 + r;
#pragma unroll
                for (int nf = 0; nf < 4; nf++) {
                    int col = w * 64 + nf * 16 + li;
                    sA2[row * PAD2 + col] = f2b(silu_f(acc2[mf][nf][r] + bb[nf]));
                }
            }
    }
    __syncthreads();

    // ---- GEMM3: act2 [64,256] @ W3[384,256]^T -> [64,384], silu, cutoff ----
    // two nf-halves (3 cols each) to bound VGPR; weights reg-double-buffered.
#pragma unroll
    for (int hn = 0; hn < 2; hn++) {
        const int cbase = w * 96 + hn * 48;
        f32x4 acc3[4][3] = {};
        bf16x8 b3v[2][3];
#pragma unroll
        for (int nf = 0; nf < 3; nf++)
            b3v[0][nf] = __builtin_bit_cast(bf16x8,
                *(const short8*)(W3 + (size_t)(cbase + nf * 16 + li) * (2 * H) + q * 8));
#pragma unroll
        for (int ks = 0; ks < 8; ks++) {
            const int cur = ks & 1;
            if (ks < 7) {
#pragma unroll
                for (int nf = 0; nf < 3; nf++)
                    b3v[cur ^ 1][nf] = __builtin_bit_cast(bf16x8,
                        *(const short8*)(W3 + (size_t)(cbase + nf * 16 + li) * (2 * H)
                                         + (ks + 1) * 32 + q * 8));
            }
            bf16x8 av[4];
#pragma unroll
            for (int mf = 0; mf < 4; mf++)
                av[mf] = __builtin_bit_cast(bf16x8,
                    *(const short8*)(sA2 + (mf * 16 + li) * PAD2 + ks * 32 + q * 8));
            __builtin_amdgcn_s_setprio(1);
#pragma unroll
            for (int mf = 0; mf < 4; mf++)
#pragma unroll
                for (int nf = 0; nf < 3; nf++)
                    acc3[mf][nf] = __builtin_amdgcn_mfma_f32_16x16x32_bf16(
                        av[mf], b3v[cur][nf], acc3[mf][nf], 0, 0, 0);
            __builtin_amdgcn_s_setprio(0);
        }
        float bb[3];
#pragma unroll
        for (int nf = 0; nf < 3; nf++) bb[nf] = b3[cbase + nf * 16 + li];
#pragma unroll
        for (int mf = 0; mf < 4; mf++)
#pragma unroll
            for (int r = 0; r < 4; r++) {
                int row = mf * 16 + q * 4 + r;
                float wv = sEW[row];
                float cs = (wv < CUTOFF_F) ? 0.5f * (__cosf(wv * PI_OVER_CUTOFF) + 1.f) : 0.f;
#pragma unroll
                for (int nf = 0; nf < 3; nf++) {
                    int col = cbase + nf * 16 + li;
                    float x = silu_f(acc3[mf][nf][r] + bb[nf]) * cs;
                    outp[(size_t)(e0 + row) * 384 + col] = f2b(x);
                }
            }
    }
}

// ---------------------------------------------------------------------------
// CSR build (once; edge_index is static across layers)
__global__ __launch_bounds__(256) void k_hist(
        const int* __restrict__ eidx, int* __restrict__ cnt) {
    int e = blockIdx.x * 256 + threadIdx.x;
    if (e < NEDGES) atomicAdd(&cnt[eidx[e]], 1);
}

__global__ __launch_bounds__(256) void k_scan(
        const int* __restrict__ cnt, int* __restrict__ rowstart,
        int* __restrict__ cursor) {
    __shared__ int partial[256];
    int t = threadIdx.x;
    int loc[8];
    int run = 0;
#pragma unroll
    for (int j = 0; j < 8; j++) {
        int v = cnt[t * 8 + j];
        loc[j] = run; run += v;
    }
    partial[t] = run;
    __syncthreads();
    if (t == 0) {
        int acc = 0;
        for (int i = 0; i < 256; i++) { int v = partial[i]; partial[i] = acc; acc += v; }
        rowstart[2048] = acc;
    }
    __syncthreads();
    int base = partial[t];
#pragma unroll
    for (int j = 0; j < 8; j++) {
        rowstart[t * 8 + j] = base + loc[j];
        cursor[t * 8 + j] = base + loc[j];
    }
}

__global__ __launch_bounds__(256) void k_fill(
        const int* __restrict__ eidx, int* __restrict__ cursor,
        int* __restrict__ elist) {
    int e = blockIdx.x * 256 + threadIdx.x;
    if (e >= NEDGES) return;
    int src = eidx[e];
    int pos = atomicAdd(&cursor[src], 1);
    elist[pos] = e;
}

// ---------------------------------------------------------------------------
// Gather + fused abnorm, v2: NH threads; adjacent lane pairs split a node's
// edge list (2x TLP, half the dependent-load chain), combine via shfl_xor,
// then each lane runs abnorm for its own h column.
__global__ __launch_bounds__(256) void k_gather_ab(
        const __hip_bfloat16* __restrict__ ea /* [E][384], col=h*3+comp */,
        const int* __restrict__ eidx,
        const int* __restrict__ rowstart, const int* __restrict__ elist,
        const __hip_bfloat16* __restrict__ Yb, const float* __restrict__ q,
        __hip_bfloat16* __restrict__ Tb) {
    int gid = blockIdx.x * 256 + threadIdx.x;   // NH threads
    int n = gid >> 7;
    int t7 = gid & 127;
    int hp = t7 >> 1;          // h-pair index 0..63
    int half = t7 & 1;         // which half of the edge list / which column
    int h0 = hp << 1;
    int beg = rowstart[n], end = rowstart[n + 1];
    const unsigned short* Y = (const unsigned short*)Yb;
    float acc[9][2];
#pragma unroll
    for (int c = 0; c < 9; c++) { acc[c][0] = 0.f; acc[c][1] = 0.f; }
    for (int idx = beg + half; idx < end; idx += 2) {
        int e = elist[idx];
        int dst = eidx[NEDGES + e];
        const unsigned short* eap = (const unsigned short*)ea + (size_t)e * 384 + h0 * 3;
        unsigned u0 = *(const unsigned*)(eap);
        unsigned u1 = *(const unsigned*)(eap + 2);
        unsigned u2 = *(const unsigned*)(eap + 4);
        float w0a = b2f(u0 & 0xffff), w1a = b2f(u0 >> 16);
        float w2a = b2f(u1 & 0xffff), w0b = b2f(u1 >> 16);
        float w1b = b2f(u2 & 0xffff), w2b = b2f(u2 >> 16);
        const unsigned short* yp = Y + (size_t)dst * NP + h0;
        ushort2 y;
        y = *(const ushort2*)(yp + 0 * H); acc[0][0] += w0a * b2f(y.x); acc[0][1] += w0b * b2f(y.y);
        y = *(const ushort2*)(yp + 1 * H); acc[1][0] += w1a * b2f(y.x); acc[1][1] += w1b * b2f(y.y);
        y = *(const ushort2*)(yp + 2 * H); acc[2][0] += w1a * b2f(y.x); acc[2][1] += w1b * b2f(y.y);
        y = *(const ushort2*)(yp + 3 * H); acc[3][0] += w1a * b2f(y.x); acc[3][1] += w1b * b2f(y.y);
#pragma unroll
        for (int c = 4; c < 9; c++) {
            y = *(const ushort2*)(yp + c * H);
            acc[c][0] += w2a * b2f(y.x); acc[c][1] += w2b * b2f(y.y);
        }
    }
    // combine the two halves (lanes differ only in bit 0)
#pragma unroll
    for (int c = 0; c < 9; c++) {
        acc[c][0] += __shfl_xor(acc[c][0], 1);
        acc[c][1] += __shfl_xor(acc[c][1], 1);
    }
    // fused abnorm: this lane handles column h0+half
    int hcol = h0 + half;
    const unsigned short* yp = Y + (size_t)n * NP + hcol;
    float scale = 1.f + 0.1f * q[n];
    float md[9], yd[9];
#pragma unroll
    for (int c = 0; c < 9; c++) {
        md[c] = acc[c][half];
        yd[c] = b2f(yp[(size_t)c * H]);
    }
    float m[9], yf[9];
    build_full(md, m);
    build_full(yd, yf);
    float ab[9];
#pragma unroll
    for (int ii = 0; ii < 3; ii++)
#pragma unroll
        for (int jj = 0; jj < 3; jj++) {
            float s = 0.f;
#pragma unroll
            for (int kk = 0; kk < 3; kk++)
                s += m[ii * 3 + kk] * yf[kk * 3 + jj] + yf[ii * 3 + kk] * m[kk * 3 + jj];
            ab[ii * 3 + jj] = s;
        }
    float nrm = 0.f;
#pragma unroll
    for (int j = 0; j < 9; j++) { ab[j] *= scale; nrm += ab[j] * ab[j]; }
    float inv = 1.f / (nrm + 1.f);
    float tr3 = (ab[0] + ab[4] + ab[8]) * (1.f / 3.f);
    unsigned short* T = (unsigned short*)Tb + (size_t)n * NP + hcol;
    T[0 * H] = f2b(tr3 * inv);
    T[1 * H] = f2b(0.5f * (ab[1] - ab[3]) * inv);
    T[2 * H] = f2b(0.5f * (ab[2] - ab[6]) * inv);
    T[3 * H] = f2b(0.5f * (ab[5] - ab[7]) * inv);
    T[4 * H] = f2b((ab[0] - tr3) * inv);
    T[5 * H] = f2b(0.5f * (ab[1] + ab[3]) * inv);
    T[6 * H] = f2b(0.5f * (ab[2] + ab[6]) * inv);
    T[7 * H] = f2b((ab[4] - tr3) * inv);
    T[8 * H] = f2b(0.5f * (ab[5] + ab[7]) * inv);
}

// ---------------------------------------------------------------------------
// Final: Xout = Xn + dX + (1+0.1q)*dX@dX.  dX interleaved bf16 [n][9][H].
// PREP: also normalize+decompose Xout into Xn (fp32) and Db (bf16) for next layer.
template <bool PREP>
__global__ __launch_bounds__(256) void k_final(
        const __hip_bfloat16* __restrict__ dXb, const float* __restrict__ Xn,
        const float* __restrict__ q, float* __restrict__ Xout,
        float* __restrict__ XnW, __hip_bfloat16* __restrict__ Db) {
    int i = blockIdx.x * 256 + threadIdx.x;
    if (i >= NH) return;
    const unsigned short* dX = (const unsigned short*)dXb + (size_t)(i >> 7) * NP + (i & 127);
    float dd[9];
#pragma unroll
    for (int c = 0; c < 9; c++) dd[c] = b2f(dX[(size_t)c * H]);
    float dx[9];
    build_full(dd, dx);
    float scale = 1.f + 0.1f * q[i >> 7];
    float out[9];
#pragma unroll
    for (int ii = 0; ii < 3; ii++)
#pragma unroll
        for (int jj = 0; jj < 3; jj++) {
            float s = 0.f;
#pragma unroll
            for (int kk = 0; kk < 3; kk++)
                s += dx[ii * 3 + kk] * dx[kk * 3 + jj];
            out[ii * 3 + jj] = Xn[(size_t)i * 9 + ii * 3 + jj] + dx[ii * 3 + jj] + scale * s;
        }
#pragma unroll
    for (int j = 0; j < 9; j++) Xout[(size_t)i * 9 + j] = out[j];
    if (PREP) {
        float ss = 0.f;
#pragma unroll
        for (int j = 0; j < 9; j++) ss += out[j] * out[j];
        float inv = 1.f / (ss + 1.f);
        float v[9];
#pragma unroll
        for (int j = 0; j < 9; j++) { v[j] = out[j] * inv; XnW[(size_t)i * 9 + j] = v[j]; }
        float i0 = (v[0] + v[4] + v[8]) * (1.f / 3.f);
        unsigned short* D = (unsigned short*)Db + (size_t)(i >> 7) * NP + (i & 127);
        D[0 * H] = f2b(i0);
        D[1 * H] = f2b(0.5f * (v[1] - v[3]));
        D[2 * H] = f2b(0.5f * (v[2] - v[6]));
        D[3 * H] = f2b(0.5f * (v[5] - v[7]));
        D[4 * H] = f2b(v[0] - i0);
        D[5 * H] = f2b(0.5f * (v[1] + v[3]));
        D[6 * H] = f2b(0.5f * (v[2] + v[6]));
        D[7 * H] = f2b(v[4] - i0);
        D[8 * H] = f2b(0.5f * (v[5] + v[7]));
    }
}

// ---------------------------------------------------------------------------
extern "C" void kernel_launch(void* const* d_in, const int* in_sizes, int n_in,
                              void* d_out, int out_size, void* d_ws, size_t ws_size,
                              hipStream_t stream) {
    const float* X          = (const float*)d_in[0];
    const float* edge_attr  = (const float*)d_in[1];
    const float* edge_weight= (const float*)d_in[2];
    const float* q          = (const float*)d_in[3];
    const float* Ws1        = (const float*)d_in[4];
    const float* bs1        = (const float*)d_in[5];
    const float* Ws2        = (const float*)d_in[6];
    const float* bs2        = (const float*)d_in[7];
    const float* Ws3        = (const float*)d_in[8];
    const float* bs3        = (const float*)d_in[9];
    const float* Wt         = (const float*)d_in[10];
    const int*   eidx       = (const int*)d_in[11];
    float* Xout = (float*)d_out;

    char* p = (char*)d_ws;
    auto alloc = [&](size_t bytes) -> char* {
        char* r = p; p += (bytes + 255) & ~(size_t)255; return r;
    };
    size_t nodeBytes = (size_t)NH * 9 * sizeof(float);
    float* Xn   = (float*)alloc(nodeBytes);
    __hip_bfloat16* Db = (__hip_bfloat16*)alloc((size_t)NH * 9 * 2);  // D / T planes
    __hip_bfloat16* Yb = (__hip_bfloat16*)alloc((size_t)NH * 9 * 2);  // Y, then dX
    __hip_bfloat16* eaB = (__hip_bfloat16*)alloc((size_t)C0 * 2);
    __hip_bfloat16* W1b = (__hip_bfloat16*)alloc((size_t)C1 * 2);
    __hip_bfloat16* W2b = (__hip_bfloat16*)alloc((size_t)C2 * 2);
    __hip_bfloat16* W3b = (__hip_bfloat16*)alloc((size_t)C3 * 2);
    __hip_bfloat16* Wtb = (__hip_bfloat16*)alloc((size_t)C4 * 2);
    __hip_bfloat16* ea3g = (__hip_bfloat16*)alloc((size_t)2 * NEDGES * 384 * 2);
    int* cnt      = (int*)alloc(2048 * 4);
    int* rowstart = (int*)alloc(2049 * 4);
    int* cursor   = (int*)alloc(2048 * 4);
    int* elist    = (int*)alloc(NEDGES * 4);

    // one-time bf16 casts (fused)
    k_cast_all<<<(C0 + C1 + C2 + C3 + C4) / 256, 256, 0, stream>>>(
        edge_attr, Ws1, Ws2, Ws3, Wt, eaB, W1b, W2b, W3b, Wtb);

    // CSR once (edge_index static across layers)
    hipMemsetAsync(cnt, 0, 2048 * sizeof(int), stream);
    k_hist<<<NEDGES / 256, 256, 0, stream>>>(eidx, cnt);
    k_scan<<<1, 256, 0, stream>>>(cnt, rowstart, cursor);
    k_fill<<<NEDGES / 256, 256, 0, stream>>>(eidx, cursor, elist);

    k_node_prep<<<NH / 256, 256, 0, stream>>>(X, Xn, Db);

    // edge MLP for BOTH layers in one launch (independent of X)
    k_mlp_fused<<<dim3(NEDGES / ETILE, 1, 2), 256, 0, stream>>>(
        eaB, W1b, W2b, W3b, bs1, bs2, bs3, edge_weight, ea3g);

    for (int l = 0; l < 2; l++) {
        const __hip_bfloat16* Wtl = Wtb + (size_t)l * 6 * H * H;
        const __hip_bfloat16* ea3 = ea3g + (size_t)l * NEDGES * 384;

        // Y = chan_mix(decomposed Xn) -> bf16 interleaved planes
        k_mix<<<dim3(NATOMS / 128, 2, 9), 256, 0, stream>>>(Db, Wtl, Yb, 0);
        // gather + fused abnorm -> Tb (reuses Db)
        k_gather_ab<<<NH / 256, 256, 0, stream>>>(
            ea3, eidx, rowstart, elist, Yb, q, Db);
        // dX = chan_mix(T) -> bf16 interleaved planes (reuses Yb)
        k_mix<<<dim3(NATOMS / 128, 2, 9), 256, 0, stream>>>(Db, Wtl, Yb, 3);
        // final (+ fused node-prep for next layer)
        if (l == 0)
            k_final<true><<<NH / 256, 256, 0, stream>>>(Yb, Xn, q, Xout, Xn, Db);
        else
            k_final<false><<<NH / 256, 256, 0, stream>>>(Yb, Xn, q, Xout, nullptr, nullptr);
    }
}